// Round 1
// baseline (3378.033 us; speedup 1.0000x reference)
//
#include <hip/hip_runtime.h>
#include <cmath>

#define Bz 2
#define Sz 1024
#define Dz 1024
#define Hz 16
#define HDz 64
#define Ez 8
#define FFz 4096
#define Nz (Bz*Sz)
#define EPSz 1e-5f

__device__ __forceinline__ float gelu_f(float x){
  return 0.5f*x*(1.0f + erff(x*0.7071067811865475f));
}

// C[M,N] = A[M,K] @ W[K,N] + bias[N] (+ res[M,N] if res != nullptr)
__global__ __launch_bounds__(256) void gemm_bias(
    const float* __restrict__ A, const float* __restrict__ W,
    const float* __restrict__ bias, const float* __restrict__ res,
    float* __restrict__ C, int M, int Nn, int Kd)
{
  __shared__ float As[16][64];
  __shared__ float Bs[16][64];
  const int t = threadIdx.x;
  const int tx = t & 15, ty = t >> 4;
  const int n0 = blockIdx.x * 64, m0 = blockIdx.y * 64;
  const int amm = t >> 2, akk = (t & 3) << 2;
  const int bkk = t >> 4, bnn = (t & 15) << 2;
  float c[4][4] = {};
  for (int k0 = 0; k0 < Kd; k0 += 16) {
    float4 av = *(const float4*)(A + (size_t)(m0+amm)*Kd + k0 + akk);
    float4 bv = *(const float4*)(W + (size_t)(k0+bkk)*Nn + n0 + bnn);
    __syncthreads();
    As[akk+0][amm] = av.x; As[akk+1][amm] = av.y;
    As[akk+2][amm] = av.z; As[akk+3][amm] = av.w;
    Bs[bkk][bnn+0] = bv.x; Bs[bkk][bnn+1] = bv.y;
    Bs[bkk][bnn+2] = bv.z; Bs[bkk][bnn+3] = bv.w;
    __syncthreads();
    #pragma unroll
    for (int kk = 0; kk < 16; ++kk) {
      float a[4], b[4];
      #pragma unroll
      for (int i = 0; i < 4; ++i) a[i] = As[kk][ty + 16*i];
      #pragma unroll
      for (int j = 0; j < 4; ++j) b[j] = Bs[kk][tx + 16*j];
      #pragma unroll
      for (int i = 0; i < 4; ++i)
        #pragma unroll
        for (int j = 0; j < 4; ++j)
          c[i][j] += a[i]*b[j];
    }
  }
  #pragma unroll
  for (int i = 0; i < 4; ++i) {
    int m = m0 + ty + 16*i;
    #pragma unroll
    for (int j = 0; j < 4; ++j) {
      int n = n0 + tx + 16*j;
      float val = c[i][j] + bias[n];
      if (res) val += res[(size_t)m*Nn + n];
      C[(size_t)m*Nn + n] = val;
    }
  }
}

// In-place RoPE on q and k laid out [N, D] = [B*S, H*HD]
__global__ void rope_qk(float* __restrict__ q, float* __restrict__ k){
  int gid = blockIdx.x*blockDim.x + threadIdx.x;
  if (gid >= Nz*Hz*32) return;
  int i = gid & 31;
  int h = (gid >> 5) & (Hz-1);
  int n = gid >> 9;          // /(16*32)
  int s = n & (Sz-1);
  float inv = powf(10000.0f, -(float)(2*i)/64.0f);
  float ang = (float)s * inv;
  float cs = cosf(ang), sn = sinf(ang);
  size_t base = (size_t)n*Dz + h*HDz + i;
  float q1 = q[base], q2 = q[base+32];
  q[base]    = q1*cs - q2*sn;
  q[base+32] = q2*cs + q1*sn;
  float k1 = k[base], k2 = k[base+32];
  k[base]    = k1*cs - k2*sn;
  k[base+32] = k2*cs + k1*sn;
}

// Flash-lite attention: 1 wave per query row, 4 waves per block.
__global__ __launch_bounds__(256) void attn_fwd(
    const float* __restrict__ q, const float* __restrict__ k,
    const float* __restrict__ v, float* __restrict__ ao)
{
  const int wave = threadIdx.x >> 6;
  const int lane = threadIdx.x & 63;
  const int idx = blockIdx.x*4 + wave;   // (b*H + h)*S + sq
  const int sq = idx & (Sz-1);
  const int bh = idx >> 10;
  const int h = bh & (Hz-1);
  const int b = bh >> 4;
  __shared__ float qs[4][64];
  const size_t hoff = (size_t)h*HDz;
  qs[wave][lane] = q[((size_t)(b*Sz+sq))*Dz + hoff + lane];
  __syncthreads();
  const float* qw = qs[wave];
  float m = -INFINITY, l = 0.f, acc = 0.f;
  for (int t0 = 0; t0 < Sz; t0 += 64) {
    const float* krow = k + ((size_t)(b*Sz + t0 + lane))*Dz + hoff;
    float s = 0.f;
    #pragma unroll 16
    for (int d = 0; d < 64; ++d) s += qw[d]*krow[d];
    s *= 0.125f;   // 1/sqrt(64)
    float tmax = s;
    #pragma unroll
    for (int off = 32; off; off >>= 1) tmax = fmaxf(tmax, __shfl_xor(tmax, off));
    float mnew = fmaxf(m, tmax);
    float rescale = __expf(m - mnew);
    float p = __expf(s - mnew);
    float psum = p;
    #pragma unroll
    for (int off = 32; off; off >>= 1) psum += __shfl_xor(psum, off);
    l = l*rescale + psum;
    acc *= rescale;
    const float* vbase = v + ((size_t)(b*Sz+t0))*Dz + hoff;
    for (int kk = 0; kk < 64; ++kk) {
      float pk = __shfl(p, kk);
      acc += pk * vbase[(size_t)kk*Dz + lane];
    }
    m = mnew;
  }
  ao[((size_t)(b*Sz+sq))*Dz + hoff + lane] = acc / l;
}

// LayerNorm over rows of D=1024; out = LN(a (+ badd)) * g + beta
__global__ __launch_bounds__(256) void layernorm_k(
    const float* __restrict__ a, const float* __restrict__ badd,
    const float* __restrict__ g, const float* __restrict__ beta,
    float* __restrict__ out)
{
  int n = blockIdx.x, t = threadIdx.x;
  __shared__ float red[256];
  float vals[4]; float s = 0.f;
  #pragma unroll
  for (int i = 0; i < 4; ++i) {
    int d = t + i*256;
    float x = a[(size_t)n*Dz + d];
    if (badd) x += badd[(size_t)n*Dz + d];
    vals[i] = x; s += x;
  }
  red[t] = s; __syncthreads();
  for (int st = 128; st; st >>= 1) { if (t < st) red[t] += red[t+st]; __syncthreads(); }
  float mean = red[0] * (1.0f/Dz);
  __syncthreads();
  float vsum = 0.f;
  #pragma unroll
  for (int i = 0; i < 4; ++i){ float dd = vals[i]-mean; vsum += dd*dd; }
  red[t] = vsum; __syncthreads();
  for (int st = 128; st; st >>= 1) { if (t < st) red[t] += red[t+st]; __syncthreads(); }
  float rs = rsqrtf(red[0]*(1.0f/Dz) + EPSz);
  #pragma unroll
  for (int i = 0; i < 4; ++i) {
    int d = t + i*256;
    out[(size_t)n*Dz + d] = (vals[i]-mean)*rs*g[d] + beta[d];
  }
}

// Gate: logits = x1 @ Wg + bg, softmax, top-2, renorm; build expert buckets.
__global__ __launch_bounds__(64) void gate_topk(
    const float* __restrict__ x1, const float* __restrict__ Wg,
    const float* __restrict__ bg, float* __restrict__ comb,
    int* __restrict__ counts, int* __restrict__ toklist)
{
  int n = blockIdx.x, lane = threadIdx.x;
  const float* row = x1 + (size_t)n*Dz;
  float acc[8] = {0,0,0,0,0,0,0,0};
  for (int d = lane; d < Dz; d += 64) {
    float xv = row[d];
    const float4* wp = (const float4*)(Wg + (size_t)d*Ez);
    float4 w0 = wp[0], w1 = wp[1];
    acc[0] += xv*w0.x; acc[1] += xv*w0.y; acc[2] += xv*w0.z; acc[3] += xv*w0.w;
    acc[4] += xv*w1.x; acc[5] += xv*w1.y; acc[6] += xv*w1.z; acc[7] += xv*w1.w;
  }
  #pragma unroll
  for (int e = 0; e < 8; ++e)
    #pragma unroll
    for (int off = 32; off; off >>= 1) acc[e] += __shfl_xor(acc[e], off);
  if (lane == 0) {
    float lg[8]; float mx = -INFINITY;
    #pragma unroll
    for (int e = 0; e < 8; ++e){ lg[e] = acc[e] + bg[e]; mx = fmaxf(mx, lg[e]); }
    float p[8];
    #pragma unroll
    for (int e = 0; e < 8; ++e) p[e] = __expf(lg[e]-mx);
    int e1 = 0; float m1 = p[0];
    for (int e = 1; e < 8; ++e) if (p[e] > m1){ m1 = p[e]; e1 = e; }
    int e2 = -1; float m2 = -INFINITY;
    for (int e = 0; e < 8; ++e) if (e != e1 && p[e] > m2){ m2 = p[e]; e2 = e; }
    float inv = 1.0f/(m1+m2);
    #pragma unroll
    for (int e = 0; e < 8; ++e) comb[(size_t)n*Ez + e] = 0.f;
    comb[(size_t)n*Ez + e1] = m1*inv;
    comb[(size_t)n*Ez + e2] = m2*inv;
    int p1 = atomicAdd(&counts[e1], 1); toklist[e1*Nz + p1] = n;
    int p2 = atomicAdd(&counts[e2], 1); toklist[e2*Nz + p2] = n;
  }
}

__global__ void prefix_k(const int* __restrict__ counts, int* __restrict__ offs){
  if (threadIdx.x == 0 && blockIdx.x == 0) {
    int s = 0;
    for (int e = 0; e < Ez; ++e){ offs[e] = s; s += counts[e]; }
    offs[Ez] = s;
  }
}

// Grouped GEMM1: h[row] = gelu(x1[tok] @ W1[e] + b1[e]) for rows of expert e
__global__ __launch_bounds__(256) void moe_gemm1(
    const float* __restrict__ x1, const float* __restrict__ W1,
    const float* __restrict__ b1, const int* __restrict__ counts,
    const int* __restrict__ offs, const int* __restrict__ toklist,
    float* __restrict__ h)
{
  const int e = blockIdx.z;
  const int cnt = counts[e];
  const int r0 = blockIdx.y * 64;
  if (r0 >= cnt) return;
  __shared__ float As[16][64];
  __shared__ float Bs[16][64];
  __shared__ int toks[64];
  const int t = threadIdx.x;
  if (t < 64) toks[t] = (r0 + t < cnt) ? toklist[e*Nz + r0 + t] : -1;
  const int tx = t & 15, ty = t >> 4;
  const int n0 = blockIdx.x * 64;
  const int amm = t >> 2, akk = (t & 3) << 2;
  const int bkk = t >> 4, bnn = (t & 15) << 2;
  const float* W1e = W1 + (size_t)e*Dz*FFz;
  float c[4][4] = {};
  __syncthreads();
  const int atok = toks[amm];
  for (int k0 = 0; k0 < Dz; k0 += 16) {
    float4 av = make_float4(0.f,0.f,0.f,0.f);
    if (atok >= 0) av = *(const float4*)(x1 + (size_t)atok*Dz + k0 + akk);
    float4 bv = *(const float4*)(W1e + (size_t)(k0+bkk)*FFz + n0 + bnn);
    __syncthreads();
    As[akk+0][amm] = av.x; As[akk+1][amm] = av.y;
    As[akk+2][amm] = av.z; As[akk+3][amm] = av.w;
    Bs[bkk][bnn+0] = bv.x; Bs[bkk][bnn+1] = bv.y;
    Bs[bkk][bnn+2] = bv.z; Bs[bkk][bnn+3] = bv.w;
    __syncthreads();
    #pragma unroll
    for (int kk = 0; kk < 16; ++kk) {
      float a[4], b[4];
      #pragma unroll
      for (int i = 0; i < 4; ++i) a[i] = As[kk][ty + 16*i];
      #pragma unroll
      for (int j = 0; j < 4; ++j) b[j] = Bs[kk][tx + 16*j];
      #pragma unroll
      for (int i = 0; i < 4; ++i)
        #pragma unroll
        for (int j = 0; j < 4; ++j)
          c[i][j] += a[i]*b[j];
    }
  }
  const int hbase = offs[e] + r0;
  #pragma unroll
  for (int i = 0; i < 4; ++i) {
    int row = ty + 16*i;
    if (toks[row] < 0) continue;
    #pragma unroll
    for (int j = 0; j < 4; ++j) {
      int n = n0 + tx + 16*j;
      float val = gelu_f(c[i][j] + b1[e*FFz + n]);
      h[(size_t)(hbase+row)*FFz + n] = val;
    }
  }
}

// Grouped GEMM2: moe[tok] += comb[tok,e] * (h[row] @ W2[e] + b2[e])
__global__ __launch_bounds__(256) void moe_gemm2(
    const float* __restrict__ h, const float* __restrict__ W2,
    const float* __restrict__ b2, const float* __restrict__ comb,
    const int* __restrict__ counts, const int* __restrict__ offs,
    const int* __restrict__ toklist, float* __restrict__ moe)
{
  const int e = blockIdx.z;
  const int cnt = counts[e];
  const int r0 = blockIdx.y * 64;
  if (r0 >= cnt) return;
  __shared__ float As[16][64];
  __shared__ float Bs[16][64];
  __shared__ int toks[64];
  const int t = threadIdx.x;
  if (t < 64) toks[t] = (r0 + t < cnt) ? toklist[e*Nz + r0 + t] : -1;
  const int tx = t & 15, ty = t >> 4;
  const int n0 = blockIdx.x * 64;
  const int amm = t >> 2, akk = (t & 3) << 2;
  const int bkk = t >> 4, bnn = (t & 15) << 2;
  const float* W2e = W2 + (size_t)e*FFz*Dz;
  const int hbase = offs[e] + r0;
  const bool avalid = (r0 + amm) < cnt;
  float c[4][4] = {};
  __syncthreads();
  for (int k0 = 0; k0 < FFz; k0 += 16) {
    float4 av = avalid ? *(const float4*)(h + (size_t)(hbase+amm)*FFz + k0 + akk)
                       : make_float4(0.f,0.f,0.f,0.f);
    float4 bv = *(const float4*)(W2e + (size_t)(k0+bkk)*Dz + n0 + bnn);
    __syncthreads();
    As[akk+0][amm] = av.x; As[akk+1][amm] = av.y;
    As[akk+2][amm] = av.z; As[akk+3][amm] = av.w;
    Bs[bkk][bnn+0] = bv.x; Bs[bkk][bnn+1] = bv.y;
    Bs[bkk][bnn+2] = bv.z; Bs[bkk][bnn+3] = bv.w;
    __syncthreads();
    #pragma unroll
    for (int kk = 0; kk < 16; ++kk) {
      float a[4], b[4];
      #pragma unroll
      for (int i = 0; i < 4; ++i) a[i] = As[kk][ty + 16*i];
      #pragma unroll
      for (int j = 0; j < 4; ++j) b[j] = Bs[kk][tx + 16*j];
      #pragma unroll
      for (int i = 0; i < 4; ++i)
        #pragma unroll
        for (int j = 0; j < 4; ++j)
          c[i][j] += a[i]*b[j];
    }
  }
  #pragma unroll
  for (int i = 0; i < 4; ++i) {
    int row = ty + 16*i;
    int tok = toks[row];
    if (tok < 0) continue;
    float w = comb[(size_t)tok*Ez + e];
    #pragma unroll
    for (int j = 0; j < 4; ++j) {
      int n = n0 + tx + 16*j;
      atomicAdd(&moe[(size_t)tok*Dz + n], w*(c[i][j] + b2[e*Dz + n]));
    }
  }
}

extern "C" void kernel_launch(void* const* d_in, const int* in_sizes, int n_in,
                              void* d_out, int out_size, void* d_ws, size_t ws_size,
                              hipStream_t stream)
{
  const float* x  = (const float*)d_in[0];
  const float* Wq = (const float*)d_in[1];
  const float* bq = (const float*)d_in[2];
  const float* Wk = (const float*)d_in[3];
  const float* bk = (const float*)d_in[4];
  const float* Wv = (const float*)d_in[5];
  const float* bv = (const float*)d_in[6];
  const float* Wo = (const float*)d_in[7];
  const float* bo = (const float*)d_in[8];
  const float* Wg = (const float*)d_in[9];
  const float* bg = (const float*)d_in[10];
  const float* W1 = (const float*)d_in[11];
  const float* b1 = (const float*)d_in[12];
  const float* W2 = (const float*)d_in[13];
  const float* b2 = (const float*)d_in[14];
  const float* g1 = (const float*)d_in[15];
  const float* be1= (const float*)d_in[16];
  const float* g2 = (const float*)d_in[17];
  const float* be2= (const float*)d_in[18];
  float* out = (float*)d_out;

  float* q    = (float*)d_ws;
  float* kbuf = q    + (size_t)Nz*Dz;
  float* vbuf = kbuf + (size_t)Nz*Dz;
  float* ao   = vbuf + (size_t)Nz*Dz;
  float* t1   = ao   + (size_t)Nz*Dz;
  float* x1   = t1   + (size_t)Nz*Dz;
  float* comb = x1   + (size_t)Nz*Dz;
  float* hbuf = comb + (size_t)Nz*Ez;
  float* moe  = hbuf + (size_t)Nz*2*FFz;
  int* counts  = (int*)(moe + (size_t)Nz*Dz);
  int* offs    = counts + Ez;
  int* toklist = offs + Ez + 1;

  dim3 blk(256);
  gemm_bias<<<dim3(Dz/64, Nz/64), blk, 0, stream>>>(x, Wq, bq, nullptr, q,    Nz, Dz, Dz);
  gemm_bias<<<dim3(Dz/64, Nz/64), blk, 0, stream>>>(x, Wk, bk, nullptr, kbuf, Nz, Dz, Dz);
  gemm_bias<<<dim3(Dz/64, Nz/64), blk, 0, stream>>>(x, Wv, bv, nullptr, vbuf, Nz, Dz, Dz);
  rope_qk<<<(Nz*Hz*32)/256, blk, 0, stream>>>(q, kbuf);
  attn_fwd<<<Bz*Hz*Sz/4, blk, 0, stream>>>(q, kbuf, vbuf, ao);
  gemm_bias<<<dim3(Dz/64, Nz/64), blk, 0, stream>>>(ao, Wo, bo, x, t1, Nz, Dz, Dz);
  layernorm_k<<<Nz, blk, 0, stream>>>(t1, nullptr, g1, be1, x1);
  hipMemsetAsync(counts, 0, Ez*sizeof(int), stream);
  hipMemsetAsync(moe, 0, (size_t)Nz*Dz*sizeof(float), stream);
  gate_topk<<<Nz, dim3(64), 0, stream>>>(x1, Wg, bg, comb, counts, toklist);
  prefix_k<<<1, dim3(64), 0, stream>>>(counts, offs);
  moe_gemm1<<<dim3(FFz/64, Nz/64, Ez), blk, 0, stream>>>(x1, W1, b1, counts, offs, toklist, hbuf);
  moe_gemm2<<<dim3(Dz/64, Nz/64, Ez), blk, 0, stream>>>(hbuf, W2, b2, comb, counts, offs, toklist, moe);
  layernorm_k<<<Nz, blk, 0, stream>>>(x1, moe, g2, be2, out);
}

// Round 2
// 2899.048 us; speedup vs baseline: 1.1652x; 1.1652x over previous
//
#include <hip/hip_runtime.h>
#include <cmath>

#define Bz 2
#define Sz 1024
#define Dz 1024
#define Hz 16
#define HDz 64
#define Ez 8
#define FFz 4096
#define Nz (Bz*Sz)
#define EPSz 1e-5f

typedef __attribute__((ext_vector_type(8))) short bf16x8;
typedef __attribute__((ext_vector_type(4))) float f32x4;
typedef __attribute__((ext_vector_type(8))) unsigned short ushortx8;

__device__ __forceinline__ float b2f(unsigned short u){
  union { unsigned int i; float f; } x; x.i = ((unsigned int)u) << 16; return x.f;
}
__device__ __forceinline__ unsigned short f2b(float f){
  union { float f; unsigned int i; } x; x.f = f;
  unsigned int r = x.i + 0x7FFFu + ((x.i >> 16) & 1u);
  return (unsigned short)(r >> 16);
}
__device__ __forceinline__ float gelu_f(float x){
  return 0.5f*x*(1.0f + erff(x*0.70710678118654752f));
}
__device__ __forceinline__ void gload16(const void* g, void* l){
  __builtin_amdgcn_global_load_lds(
    (const __attribute__((address_space(1))) unsigned int*)g,
    (__attribute__((address_space(3))) unsigned int*)l, 16, 0, 0);
}

// ---------------- fp32 -> bf16 plain convert ----------------
__global__ __launch_bounds__(256) void cvt_bf16(
    const float* __restrict__ in, unsigned short* __restrict__ out, int n)
{
  int i = (blockIdx.x*blockDim.x + threadIdx.x)*4;
  if (i >= n) return;
  float4 v = *(const float4*)(in + i);
  ushort4 o;
  o.x = f2b(v.x); o.y = f2b(v.y); o.z = f2b(v.z); o.w = f2b(v.w);
  *(ushort4*)(out + i) = o;
}

// ---------------- fp32 [z][R][C] -> bf16 [z][C][R] ----------------
__global__ __launch_bounds__(256) void transpose_cvt(
    const float* __restrict__ in, unsigned short* __restrict__ out, int R, int C)
{
  __shared__ float tile[32][33];
  const size_t boff = (size_t)blockIdx.z * R * C;
  int c0 = blockIdx.x*32, r0 = blockIdx.y*32;
  int tx = threadIdx.x & 31, ty = threadIdx.x >> 5;
  #pragma unroll
  for (int i = 0; i < 4; ++i)
    tile[ty + 8*i][tx] = in[boff + (size_t)(r0+ty+8*i)*C + c0 + tx];
  __syncthreads();
  #pragma unroll
  for (int i = 0; i < 4; ++i)
    out[boff + (size_t)(c0+ty+8*i)*R + r0 + tx] = f2b(tile[tx][ty+8*i]);
}

// ---------------- MFMA 128x128xK core (4 waves, 16x16x32 bf16) ----------------
// LDS layout: A region [kc][row] 16B chunks (slot = kc*128+row), B region same with col.
__device__ __forceinline__ void mfma_kloop(
    const unsigned short* __restrict__ pA0, const unsigned short* __restrict__ pA1,
    const unsigned short* __restrict__ pB0, const unsigned short* __restrict__ pB1,
    char* lds, int t, int K, f32x4 acc[4][4])
{
  char* dA0 = lds + t*16;
  char* dA1 = lds + (256+t)*16;
  char* dB0 = lds + 8192 + t*16;
  char* dB1 = lds + 8192 + (256+t)*16;
  const int lane = t & 63, w = t >> 6;
  const int wr = (w >> 1) << 6, wc = (w & 1) << 6;
  const int iA = (lane >> 4)*128 + wr + (lane & 15);
  const int iB = (lane >> 4)*128 + wc + (lane & 15);
  const bf16x8* fA = (const bf16x8*)lds;
  const bf16x8* fB = (const bf16x8*)(lds + 8192);
  for (int k0 = 0; k0 < K; k0 += 32) {
    __syncthreads();
    gload16(pA0 + k0, dA0);
    gload16(pA1 + k0, dA1);
    gload16(pB0 + k0, dB0);
    gload16(pB1 + k0, dB1);
    __syncthreads();
    bf16x8 a[4], b[4];
    #pragma unroll
    for (int m = 0; m < 4; ++m) a[m] = fA[iA + m*16];
    #pragma unroll
    for (int n = 0; n < 4; ++n) b[n] = fB[iB + n*16];
    #pragma unroll
    for (int m = 0; m < 4; ++m)
      #pragma unroll
      for (int n = 0; n < 4; ++n)
        acc[m][n] = __builtin_amdgcn_mfma_f32_16x16x32_bf16(a[m], b[n], acc[m][n], 0, 0, 0);
  }
}

// ---------------- dense projection GEMM: C = A[M,K] @ Wt^T + bias ----------------
// Wt is [N,K] bf16. If outf != null: out fp32 with residual res; else out bf16.
__global__ __launch_bounds__(256) void gemm_proj(
    const unsigned short* __restrict__ A, const unsigned short* __restrict__ Bt,
    const float* __restrict__ bias, const float* __restrict__ res,
    float* __restrict__ outf, unsigned short* __restrict__ outb,
    int M, int Nn, int K)
{
  __shared__ __align__(16) char lds[16384];
  const int t = threadIdx.x;
  const int m0 = blockIdx.y*128, n0 = blockIdx.x*128;
  const int ridx = t & 127, kc = t >> 7;
  const unsigned short* pA0 = A + (size_t)(m0 + ridx)*K + kc*8;
  const unsigned short* pB0 = Bt + (size_t)(n0 + ridx)*K + kc*8;
  f32x4 acc[4][4] = {};
  mfma_kloop(pA0, pA0+16, pB0, pB0+16, lds, t, K, acc);
  const int lane = t & 63, w = t >> 6;
  const int wr = (w>>1)<<6, wc = (w&1)<<6, lq = lane>>4, lr = lane&15;
  #pragma unroll
  for (int m = 0; m < 4; ++m)
    #pragma unroll
    for (int r = 0; r < 4; ++r) {
      int row = m0 + wr + m*16 + lq*4 + r;
      #pragma unroll
      for (int n = 0; n < 4; ++n) {
        int col = n0 + wc + n*16 + lr;
        float val = acc[m][n][r] + bias[col];
        if (outf) { val += res[(size_t)row*Nn + col]; outf[(size_t)row*Nn + col] = val; }
        else outb[(size_t)row*Nn + col] = f2b(val);
      }
    }
}

// ---------------- grouped MoE GEMM1: hb[slot] = gelu(x1b[tok] @ W1t[e]^T + b1[e]) ----------------
__global__ __launch_bounds__(256) void moe_gemm1(
    const unsigned short* __restrict__ x1b, const unsigned short* __restrict__ W1t,
    const float* __restrict__ b1, const int* __restrict__ counts,
    const int* __restrict__ offs, const int* __restrict__ toklist,
    unsigned short* __restrict__ hb)
{
  const int e = blockIdx.z, cnt = counts[e], r0 = blockIdx.y*128;
  if (r0 >= cnt) return;
  __shared__ __align__(16) char lds[16384];
  const int t = threadIdx.x, n0 = blockIdx.x*128;
  const int ridx = t & 127, kc = t >> 7;
  const int rg = r0 + ridx;
  const int tok = toklist[e*Nz + (rg < cnt ? rg : 0)];
  const unsigned short* pA0 = x1b + (size_t)tok*Dz + kc*8;
  const unsigned short* pB0 = W1t + ((size_t)e*FFz + n0 + ridx)*Dz + kc*8;
  f32x4 acc[4][4] = {};
  mfma_kloop(pA0, pA0+16, pB0, pB0+16, lds, t, Dz, acc);
  const int lane = t & 63, w = t >> 6;
  const int wr = (w>>1)<<6, wc = (w&1)<<6, lq = lane>>4, lr = lane&15;
  const int base = offs[e] + r0;
  #pragma unroll
  for (int m = 0; m < 4; ++m)
    #pragma unroll
    for (int r = 0; r < 4; ++r) {
      int row = wr + m*16 + lq*4 + r;
      if (r0 + row >= cnt) continue;
      #pragma unroll
      for (int n = 0; n < 4; ++n) {
        int col = n0 + wc + n*16 + lr;
        hb[(size_t)(base+row)*FFz + col] = f2b(gelu_f(acc[m][n][r] + b1[e*FFz + col]));
      }
    }
}

// ---------------- grouped MoE GEMM2: y[slot] = hb[slot] @ W2t[e]^T + b2[e] ----------------
__global__ __launch_bounds__(256) void moe_gemm2(
    const unsigned short* __restrict__ hb, const unsigned short* __restrict__ W2t,
    const float* __restrict__ b2, const int* __restrict__ counts,
    const int* __restrict__ offs, float* __restrict__ y)
{
  const int e = blockIdx.z, cnt = counts[e], r0 = blockIdx.y*128;
  if (r0 >= cnt) return;
  __shared__ __align__(16) char lds[16384];
  const int t = threadIdx.x, n0 = blockIdx.x*128;
  const int ridx = t & 127, kc = t >> 7;
  const int rg = r0 + ridx;
  const int slot = offs[e] + (rg < cnt ? rg : 0);
  const unsigned short* pA0 = hb + (size_t)slot*FFz + kc*8;
  const unsigned short* pB0 = W2t + ((size_t)e*Dz + n0 + ridx)*FFz + kc*8;
  f32x4 acc[4][4] = {};
  mfma_kloop(pA0, pA0+16, pB0, pB0+16, lds, t, FFz, acc);
  const int lane = t & 63, w = t >> 6;
  const int wr = (w>>1)<<6, wc = (w&1)<<6, lq = lane>>4, lr = lane&15;
  const int base = offs[e] + r0;
  #pragma unroll
  for (int m = 0; m < 4; ++m)
    #pragma unroll
    for (int r = 0; r < 4; ++r) {
      int row = wr + m*16 + lq*4 + r;
      if (r0 + row >= cnt) continue;
      #pragma unroll
      for (int n = 0; n < 4; ++n) {
        int col = n0 + wc + n*16 + lr;
        y[(size_t)(base+row)*Dz + col] = acc[m][n][r] + b2[e*Dz + col];
      }
    }
}

// ---------------- RoPE (in-place, bf16) ----------------
__global__ void rope_qk(unsigned short* __restrict__ q, unsigned short* __restrict__ k){
  int gid = blockIdx.x*blockDim.x + threadIdx.x;
  int i = gid & 31;
  int h = (gid >> 5) & (Hz-1);
  int n = gid >> 9;
  int s = n & (Sz-1);
  float inv = powf(10000.0f, -(float)(2*i)/64.0f);
  float ang = (float)s * inv;
  float cs = cosf(ang), sn = sinf(ang);
  size_t base = (size_t)n*Dz + h*HDz + i;
  float q1 = b2f(q[base]), q2 = b2f(q[base+32]);
  q[base]    = f2b(q1*cs - q2*sn);
  q[base+32] = f2b(q2*cs + q1*sn);
  float k1 = b2f(k[base]), k2 = b2f(k[base+32]);
  k[base]    = f2b(k1*cs - k2*sn);
  k[base+32] = f2b(k2*cs + k1*sn);
}

// ---------------- attention: 4 q-rows per wave, bf16 in/out ----------------
__global__ __launch_bounds__(256) void attn_fwd(
    const unsigned short* __restrict__ q, const unsigned short* __restrict__ k,
    const unsigned short* __restrict__ v, unsigned short* __restrict__ ao)
{
  __shared__ float qs[4][4][64];
  __shared__ float ps[4][64][4];
  const int wv = threadIdx.x >> 6, lane = threadIdx.x & 63;
  const int gw = blockIdx.x*4 + wv;
  const int bh = gw >> 8, g = gw & 255;
  const int h = bh & (Hz-1), b = bh >> 4;
  const int sq0 = g*4;
  const size_t hoff = (size_t)h*HDz;
  #pragma unroll
  for (int r = 0; r < 4; ++r)
    qs[wv][r][lane] = b2f(q[((size_t)(b*Sz+sq0+r))*Dz + hoff + lane]);
  __syncthreads();
  float mv[4] = {-INFINITY,-INFINITY,-INFINITY,-INFINITY};
  float lsum[4] = {0,0,0,0};
  float acc[4] = {0,0,0,0};
  for (int t0 = 0; t0 < Sz; t0 += 64) {
    const unsigned short* kt = k + ((size_t)(b*Sz + t0 + lane))*Dz + hoff;
    float s[4] = {0,0,0,0};
    #pragma unroll
    for (int dc = 0; dc < 8; ++dc) {
      ushortx8 kv = *(const ushortx8*)(kt + dc*8);
      #pragma unroll
      for (int j = 0; j < 8; ++j) {
        float kf = b2f(kv[j]);
        int d = dc*8 + j;
        s[0] += qs[wv][0][d]*kf;
        s[1] += qs[wv][1][d]*kf;
        s[2] += qs[wv][2][d]*kf;
        s[3] += qs[wv][3][d]*kf;
      }
    }
    float resc[4], psum[4];
    #pragma unroll
    for (int r = 0; r < 4; ++r) {
      float sv = s[r]*0.125f;
      float tm = sv;
      #pragma unroll
      for (int off = 32; off; off >>= 1) tm = fmaxf(tm, __shfl_xor(tm, off));
      float mn = fmaxf(mv[r], tm);
      resc[r] = __expf(mv[r] - mn);
      float p = __expf(sv - mn);
      mv[r] = mn;
      ps[wv][lane][r] = p;
      float su = p;
      #pragma unroll
      for (int off = 32; off; off >>= 1) su += __shfl_xor(su, off);
      psum[r] = su;
    }
    #pragma unroll
    for (int r = 0; r < 4; ++r) {
      lsum[r] = lsum[r]*resc[r] + psum[r];
      acc[r] *= resc[r];
    }
    const unsigned short* vt = v + ((size_t)(b*Sz + t0))*Dz + hoff + lane;
    #pragma unroll 8
    for (int kk = 0; kk < 64; ++kk) {
      float vv = b2f(vt[(size_t)kk*Dz]);
      float4 pp = *(const float4*)&ps[wv][kk][0];
      acc[0] += pp.x*vv; acc[1] += pp.y*vv; acc[2] += pp.z*vv; acc[3] += pp.w*vv;
    }
  }
  #pragma unroll
  for (int r = 0; r < 4; ++r)
    ao[((size_t)(b*Sz+sq0+r))*Dz + hoff + lane] = f2b(acc[r]/lsum[r]);
}

// ---------------- LayerNorm 1: out fp32 + bf16 ----------------
__global__ __launch_bounds__(256) void ln1_k(
    const float* __restrict__ a, const float* __restrict__ g,
    const float* __restrict__ beta, float* __restrict__ outf,
    unsigned short* __restrict__ outb)
{
  int n = blockIdx.x, t = threadIdx.x;
  __shared__ float red[256];
  float vals[4]; float s = 0.f;
  #pragma unroll
  for (int i = 0; i < 4; ++i) {
    int d = t + i*256;
    float x = a[(size_t)n*Dz + d];
    vals[i] = x; s += x;
  }
  red[t] = s; __syncthreads();
  for (int st = 128; st; st >>= 1) { if (t < st) red[t] += red[t+st]; __syncthreads(); }
  float mean = red[0] * (1.0f/Dz);
  __syncthreads();
  float vsum = 0.f;
  #pragma unroll
  for (int i = 0; i < 4; ++i){ float dd = vals[i]-mean; vsum += dd*dd; }
  red[t] = vsum; __syncthreads();
  for (int st = 128; st; st >>= 1) { if (t < st) red[t] += red[t+st]; __syncthreads(); }
  float rs = rsqrtf(red[0]*(1.0f/Dz) + EPSz);
  #pragma unroll
  for (int i = 0; i < 4; ++i) {
    int d = t + i*256;
    float o = (vals[i]-mean)*rs*g[d] + beta[d];
    outf[(size_t)n*Dz + d] = o;
    outb[(size_t)n*Dz + d] = f2b(o);
  }
}

// ---------------- gate: logits, softmax, top-2, bucket build ----------------
__global__ __launch_bounds__(64) void gate_topk(
    const float* __restrict__ x1, const float* __restrict__ Wg,
    const float* __restrict__ bg, int* __restrict__ counts,
    int* __restrict__ toklist, int4* __restrict__ tokinfo,
    float2* __restrict__ tokw)
{
  int n = blockIdx.x, lane = threadIdx.x;
  const float* row = x1 + (size_t)n*Dz;
  float acc[8] = {0,0,0,0,0,0,0,0};
  for (int d = lane; d < Dz; d += 64) {
    float xv = row[d];
    const float4* wp = (const float4*)(Wg + (size_t)d*Ez);
    float4 w0 = wp[0], w1 = wp[1];
    acc[0] += xv*w0.x; acc[1] += xv*w0.y; acc[2] += xv*w0.z; acc[3] += xv*w0.w;
    acc[4] += xv*w1.x; acc[5] += xv*w1.y; acc[6] += xv*w1.z; acc[7] += xv*w1.w;
  }
  #pragma unroll
  for (int e = 0; e < 8; ++e)
    #pragma unroll
    for (int off = 32; off; off >>= 1) acc[e] += __shfl_xor(acc[e], off);
  if (lane == 0) {
    float lg[8]; float mx = -INFINITY;
    #pragma unroll
    for (int e = 0; e < 8; ++e){ lg[e] = acc[e] + bg[e]; mx = fmaxf(mx, lg[e]); }
    float p[8];
    #pragma unroll
    for (int e = 0; e < 8; ++e) p[e] = __expf(lg[e]-mx);
    int e1 = 0; float m1 = p[0];
    for (int e = 1; e < 8; ++e) if (p[e] > m1){ m1 = p[e]; e1 = e; }
    int e2 = -1; float m2 = -INFINITY;
    for (int e = 0; e < 8; ++e) if (e != e1 && p[e] > m2){ m2 = p[e]; e2 = e; }
    float inv = 1.0f/(m1+m2);
    int p1 = atomicAdd(&counts[e1], 1); toklist[e1*Nz + p1] = n;
    int p2 = atomicAdd(&counts[e2], 1); toklist[e2*Nz + p2] = n;
    tokinfo[n] = make_int4(e1, p1, e2, p2);
    tokw[n] = make_float2(m1*inv, m2*inv);
  }
}

__global__ void prefix_k(const int* __restrict__ counts, int* __restrict__ offs){
  if (threadIdx.x == 0 && blockIdx.x == 0) {
    int s = 0;
    for (int e = 0; e < Ez; ++e){ offs[e] = s; s += counts[e]; }
    offs[Ez] = s;
  }
}

// ---------------- final combine + LayerNorm ----------------
__global__ __launch_bounds__(256) void ln2_k(
    const float* __restrict__ x1, const float* __restrict__ y,
    const int4* __restrict__ tokinfo, const float2* __restrict__ tokw,
    const int* __restrict__ offs, const float* __restrict__ g,
    const float* __restrict__ beta, float* __restrict__ out)
{
  int n = blockIdx.x, t = threadIdx.x;
  __shared__ float red[256];
  int4 ti = tokinfo[n]; float2 tw = tokw[n];
  const float* y1 = y + (size_t)(offs[ti.x] + ti.y)*Dz;
  const float* y2 = y + (size_t)(offs[ti.z] + ti.w)*Dz;
  float vals[4]; float s = 0.f;
  #pragma unroll
  for (int i = 0; i < 4; ++i) {
    int d = t + i*256;
    float x = x1[(size_t)n*Dz + d] + tw.x*y1[d] + tw.y*y2[d];
    vals[i] = x; s += x;
  }
  red[t] = s; __syncthreads();
  for (int st = 128; st; st >>= 1) { if (t < st) red[t] += red[t+st]; __syncthreads(); }
  float mean = red[0] * (1.0f/Dz);
  __syncthreads();
  float vsum = 0.f;
  #pragma unroll
  for (int i = 0; i < 4; ++i){ float dd = vals[i]-mean; vsum += dd*dd; }
  red[t] = vsum; __syncthreads();
  for (int st = 128; st; st >>= 1) { if (t < st) red[t] += red[t+st]; __syncthreads(); }
  float rs = rsqrtf(red[0]*(1.0f/Dz) + EPSz);
  #pragma unroll
  for (int i = 0; i < 4; ++i) {
    int d = t + i*256;
    out[(size_t)n*Dz + d] = (vals[i]-mean)*rs*g[d] + beta[d];
  }
}

extern "C" void kernel_launch(void* const* d_in, const int* in_sizes, int n_in,
                              void* d_out, int out_size, void* d_ws, size_t ws_size,
                              hipStream_t stream)
{
  const float* x  = (const float*)d_in[0];
  const float* Wq = (const float*)d_in[1];
  const float* bq = (const float*)d_in[2];
  const float* Wk = (const float*)d_in[3];
  const float* bk = (const float*)d_in[4];
  const float* Wv = (const float*)d_in[5];
  const float* bv = (const float*)d_in[6];
  const float* Wo = (const float*)d_in[7];
  const float* bo = (const float*)d_in[8];
  const float* Wg = (const float*)d_in[9];
  const float* bg = (const float*)d_in[10];
  const float* W1 = (const float*)d_in[11];
  const float* b1 = (const float*)d_in[12];
  const float* W2 = (const float*)d_in[13];
  const float* b2 = (const float*)d_in[14];
  const float* g1 = (const float*)d_in[15];
  const float* be1= (const float*)d_in[16];
  const float* g2 = (const float*)d_in[17];
  const float* be2= (const float*)d_in[18];
  float* out = (float*)d_out;

  const size_t PD = (size_t)Dz*Dz;        // 1M elems
  const size_t ND = (size_t)Nz*Dz;        // 2M elems
  unsigned short* Wqt = (unsigned short*)d_ws;
  unsigned short* Wkt = Wqt + PD;
  unsigned short* Wvt = Wkt + PD;
  unsigned short* Wot = Wvt + PD;
  unsigned short* W1t = Wot + PD;
  unsigned short* W2t = W1t + (size_t)Ez*FFz*Dz;
  unsigned short* hb  = W2t + (size_t)Ez*FFz*Dz;
  unsigned short* xb  = hb  + (size_t)2*Nz*FFz;
  unsigned short* qb  = xb  + ND;
  unsigned short* kb  = qb  + ND;
  unsigned short* vb  = kb  + ND;
  unsigned short* aob = vb  + ND;
  unsigned short* x1b = aob + ND;
  float* x1 = (float*)(x1b + ND);
  float* y  = x1 + ND;                 // 2*Nz*Dz floats
  float* t1 = y;                       // alias: t1 dead before y is written
  int4*  tokinfo = (int4*)(y + (size_t)2*Nz*Dz);
  float2* tokw   = (float2*)(tokinfo + Nz);
  int* counts  = (int*)(tokw + Nz);
  int* offs    = counts + Ez;
  int* toklist = offs + Ez + 1;

  dim3 blk(256);
  // weight conversion (transpose to [N,K] bf16)
  transpose_cvt<<<dim3(32,32,1), blk, 0, stream>>>(Wq, Wqt, Dz, Dz);
  transpose_cvt<<<dim3(32,32,1), blk, 0, stream>>>(Wk, Wkt, Dz, Dz);
  transpose_cvt<<<dim3(32,32,1), blk, 0, stream>>>(Wv, Wvt, Dz, Dz);
  transpose_cvt<<<dim3(32,32,1), blk, 0, stream>>>(Wo, Wot, Dz, Dz);
  transpose_cvt<<<dim3(FFz/32, Dz/32, Ez), blk, 0, stream>>>(W1, W1t, Dz, FFz);
  transpose_cvt<<<dim3(Dz/32, FFz/32, Ez), blk, 0, stream>>>(W2, W2t, FFz, Dz);
  cvt_bf16<<<(int)(ND/4/256), blk, 0, stream>>>(x, xb, (int)ND);

  // QKV projections (bf16 out)
  gemm_proj<<<dim3(Dz/128, Nz/128), blk, 0, stream>>>(xb, Wqt, bq, nullptr, nullptr, qb, Nz, Dz, Dz);
  gemm_proj<<<dim3(Dz/128, Nz/128), blk, 0, stream>>>(xb, Wkt, bk, nullptr, nullptr, kb, Nz, Dz, Dz);
  gemm_proj<<<dim3(Dz/128, Nz/128), blk, 0, stream>>>(xb, Wvt, bv, nullptr, nullptr, vb, Nz, Dz, Dz);
  rope_qk<<<(Nz*Hz*32)/256, blk, 0, stream>>>(qb, kb);
  attn_fwd<<<Bz*Hz*Sz/16, blk, 0, stream>>>(qb, kb, vb, aob);
  // O projection + residual (fp32 out into t1)
  gemm_proj<<<dim3(Dz/128, Nz/128), blk, 0, stream>>>(aob, Wot, bo, x, t1, nullptr, Nz, Dz, Dz);
  ln1_k<<<Nz, blk, 0, stream>>>(t1, g1, be1, x1, x1b);

  hipMemsetAsync(counts, 0, Ez*sizeof(int), stream);
  gate_topk<<<Nz, dim3(64), 0, stream>>>(x1, Wg, bg, counts, toklist, tokinfo, tokw);
  prefix_k<<<1, dim3(64), 0, stream>>>(counts, offs);
  moe_gemm1<<<dim3(FFz/128, Nz/128, Ez), blk, 0, stream>>>(x1b, W1t, b1, counts, offs, toklist, hb);
  moe_gemm2<<<dim3(Dz/128, Nz/128, Ez), blk, 0, stream>>>(hb, W2t, b2, counts, offs, y);
  ln2_k<<<Nz, blk, 0, stream>>>(x1, y, tokinfo, tokw, offs, g2, be2, out);
}

// Round 3
// 727.274 us; speedup vs baseline: 4.6448x; 3.9862x over previous
//
#include <hip/hip_runtime.h>
#include <cmath>

#define Bz 2
#define Sz 1024
#define Dz 1024
#define Hz 16
#define HDz 64
#define Ez 8
#define FFz 4096
#define Nz (Bz*Sz)
#define EPSz 1e-5f

typedef __attribute__((ext_vector_type(8))) short bf16x8;
typedef __attribute__((ext_vector_type(4))) short bf16x4;
typedef __attribute__((ext_vector_type(4))) float f32x4;
typedef __attribute__((ext_vector_type(8))) unsigned short ushortx8;

__device__ __forceinline__ float b2f(unsigned short u){
  union { unsigned int i; float f; } x; x.i = ((unsigned int)u) << 16; return x.f;
}
__device__ __forceinline__ unsigned short f2b(float f){
  union { float f; unsigned int i; } x; x.f = f;
  unsigned int r = x.i + 0x7FFFu + ((x.i >> 16) & 1u);
  return (unsigned short)(r >> 16);
}
__device__ __forceinline__ float gelu_f(float x){
  return 0.5f*x*(1.0f + erff(x*0.70710678118654752f));
}
__device__ __forceinline__ void gload16(const void* g, void* l){
  __builtin_amdgcn_global_load_lds(
    (const __attribute__((address_space(1))) unsigned int*)g,
    (__attribute__((address_space(3))) unsigned int*)l, 16, 0, 0);
}

// ---------------- fp32 -> bf16 plain convert ----------------
__global__ __launch_bounds__(256) void cvt_bf16(
    const float* __restrict__ in, unsigned short* __restrict__ out, int n)
{
  int i = (blockIdx.x*blockDim.x + threadIdx.x)*4;
  if (i >= n) return;
  float4 v = *(const float4*)(in + i);
  ushort4 o;
  o.x = f2b(v.x); o.y = f2b(v.y); o.z = f2b(v.z); o.w = f2b(v.w);
  *(ushort4*)(out + i) = o;
}

// ---------------- fp32 [z][R][C] -> bf16 [z][C][R] ----------------
__global__ __launch_bounds__(256) void transpose_cvt(
    const float* __restrict__ in, unsigned short* __restrict__ out, int R, int C)
{
  __shared__ float tile[32][33];
  const size_t boff = (size_t)blockIdx.z * R * C;
  int c0 = blockIdx.x*32, r0 = blockIdx.y*32;
  int tx = threadIdx.x & 31, ty = threadIdx.x >> 5;
  #pragma unroll
  for (int i = 0; i < 4; ++i)
    tile[ty + 8*i][tx] = in[boff + (size_t)(r0+ty+8*i)*C + c0 + tx];
  __syncthreads();
  #pragma unroll
  for (int i = 0; i < 4; ++i)
    out[boff + (size_t)(c0+ty+8*i)*R + r0 + tx] = f2b(tile[tx][ty+8*i]);
}

// ---------------- MFMA 128x128xK core (4 waves, 16x16x32 bf16) ----------------
__device__ __forceinline__ void mfma_kloop(
    const unsigned short* __restrict__ pA0, const unsigned short* __restrict__ pA1,
    const unsigned short* __restrict__ pB0, const unsigned short* __restrict__ pB1,
    char* lds, int t, int K, f32x4 acc[4][4])
{
  char* dA0 = lds + t*16;
  char* dA1 = lds + (256+t)*16;
  char* dB0 = lds + 8192 + t*16;
  char* dB1 = lds + 8192 + (256+t)*16;
  const int lane = t & 63, w = t >> 6;
  const int wr = (w >> 1) << 6, wc = (w & 1) << 6;
  const int iA = (lane >> 4)*128 + wr + (lane & 15);
  const int iB = (lane >> 4)*128 + wc + (lane & 15);
  const bf16x8* fA = (const bf16x8*)lds;
  const bf16x8* fB = (const bf16x8*)(lds + 8192);
  for (int k0 = 0; k0 < K; k0 += 32) {
    __syncthreads();
    gload16(pA0 + k0, dA0);
    gload16(pA1 + k0, dA1);
    gload16(pB0 + k0, dB0);
    gload16(pB1 + k0, dB1);
    __syncthreads();
    bf16x8 a[4], b[4];
    #pragma unroll
    for (int m = 0; m < 4; ++m) a[m] = fA[iA + m*16];
    #pragma unroll
    for (int n = 0; n < 4; ++n) b[n] = fB[iB + n*16];
    #pragma unroll
    for (int m = 0; m < 4; ++m)
      #pragma unroll
      for (int n = 0; n < 4; ++n)
        acc[m][n] = __builtin_amdgcn_mfma_f32_16x16x32_bf16(a[m], b[n], acc[m][n], 0, 0, 0);
  }
}

// ---------------- dense projection GEMM ----------------
__global__ __launch_bounds__(256) void gemm_proj(
    const unsigned short* __restrict__ A, const unsigned short* __restrict__ Bt,
    const float* __restrict__ bias, const float* __restrict__ res,
    float* __restrict__ outf, unsigned short* __restrict__ outb,
    int M, int Nn, int K)
{
  __shared__ __align__(16) char lds[16384];
  const int t = threadIdx.x;
  const int m0 = blockIdx.y*128, n0 = blockIdx.x*128;
  const int ridx = t & 127, kc = t >> 7;
  const unsigned short* pA0 = A + (size_t)(m0 + ridx)*K + kc*8;
  const unsigned short* pB0 = Bt + (size_t)(n0 + ridx)*K + kc*8;
  f32x4 acc[4][4] = {};
  mfma_kloop(pA0, pA0+16, pB0, pB0+16, lds, t, K, acc);
  const int lane = t & 63, w = t >> 6;
  const int wr = (w>>1)<<6, wc = (w&1)<<6, lq = lane>>4, lr = lane&15;
  #pragma unroll
  for (int m = 0; m < 4; ++m)
    #pragma unroll
    for (int r = 0; r < 4; ++r) {
      int row = m0 + wr + m*16 + lq*4 + r;
      #pragma unroll
      for (int n = 0; n < 4; ++n) {
        int col = n0 + wc + n*16 + lr;
        float val = acc[m][n][r] + bias[col];
        if (outf) { val += res[(size_t)row*Nn + col]; outf[(size_t)row*Nn + col] = val; }
        else outb[(size_t)row*Nn + col] = f2b(val);
      }
    }
}

// ---------------- grouped MoE GEMM1 ----------------
__global__ __launch_bounds__(256) void moe_gemm1(
    const unsigned short* __restrict__ x1b, const unsigned short* __restrict__ W1t,
    const float* __restrict__ b1, const int* __restrict__ counts,
    const int* __restrict__ offs, const int* __restrict__ toklist,
    unsigned short* __restrict__ hb)
{
  const int e = blockIdx.z, cnt = counts[e], r0 = blockIdx.y*128;
  if (r0 >= cnt) return;
  __shared__ __align__(16) char lds[16384];
  const int t = threadIdx.x, n0 = blockIdx.x*128;
  const int ridx = t & 127, kc = t >> 7;
  const int rg = r0 + ridx;
  const int tok = toklist[e*Nz + (rg < cnt ? rg : 0)];
  const unsigned short* pA0 = x1b + (size_t)tok*Dz + kc*8;
  const unsigned short* pB0 = W1t + ((size_t)e*FFz + n0 + ridx)*Dz + kc*8;
  f32x4 acc[4][4] = {};
  mfma_kloop(pA0, pA0+16, pB0, pB0+16, lds, t, Dz, acc);
  const int lane = t & 63, w = t >> 6;
  const int wr = (w>>1)<<6, wc = (w&1)<<6, lq = lane>>4, lr = lane&15;
  const int base = offs[e] + r0;
  #pragma unroll
  for (int m = 0; m < 4; ++m)
    #pragma unroll
    for (int r = 0; r < 4; ++r) {
      int row = wr + m*16 + lq*4 + r;
      if (r0 + row >= cnt) continue;
      #pragma unroll
      for (int n = 0; n < 4; ++n) {
        int col = n0 + wc + n*16 + lr;
        hb[(size_t)(base+row)*FFz + col] = f2b(gelu_f(acc[m][n][r] + b1[e*FFz + col]));
      }
    }
}

// ---------------- grouped MoE GEMM2 ----------------
__global__ __launch_bounds__(256) void moe_gemm2(
    const unsigned short* __restrict__ hb, const unsigned short* __restrict__ W2t,
    const float* __restrict__ b2, const int* __restrict__ counts,
    const int* __restrict__ offs, float* __restrict__ y)
{
  const int e = blockIdx.z, cnt = counts[e], r0 = blockIdx.y*128;
  if (r0 >= cnt) return;
  __shared__ __align__(16) char lds[16384];
  const int t = threadIdx.x, n0 = blockIdx.x*128;
  const int ridx = t & 127, kc = t >> 7;
  const int rg = r0 + ridx;
  const int slot = offs[e] + (rg < cnt ? rg : 0);
  const unsigned short* pA0 = hb + (size_t)slot*FFz + kc*8;
  const unsigned short* pB0 = W2t + ((size_t)e*Dz + n0 + ridx)*FFz + kc*8;
  f32x4 acc[4][4] = {};
  mfma_kloop(pA0, pA0+16, pB0, pB0+16, lds, t, FFz, acc);
  const int lane = t & 63, w = t >> 6;
  const int wr = (w>>1)<<6, wc = (w&1)<<6, lq = lane>>4, lr = lane&15;
  const int base = offs[e] + r0;
  #pragma unroll
  for (int m = 0; m < 4; ++m)
    #pragma unroll
    for (int r = 0; r < 4; ++r) {
      int row = wr + m*16 + lq*4 + r;
      if (r0 + row >= cnt) continue;
      #pragma unroll
      for (int n = 0; n < 4; ++n) {
        int col = n0 + wc + n*16 + lr;
        y[(size_t)(base+row)*Dz + col] = acc[m][n][r] + b2[e*Dz + col];
      }
    }
}

// ---------------- RoPE (in-place, bf16) ----------------
__global__ void rope_qk(unsigned short* __restrict__ q, unsigned short* __restrict__ k){
  int gid = blockIdx.x*blockDim.x + threadIdx.x;
  int i = gid & 31;
  int h = (gid >> 5) & (Hz-1);
  int n = gid >> 9;
  int s = n & (Sz-1);
  float inv = powf(10000.0f, -(float)(2*i)/64.0f);
  float ang = (float)s * inv;
  float cs = cosf(ang), sn = sinf(ang);
  size_t base = (size_t)n*Dz + h*HDz + i;
  float q1 = b2f(q[base]), q2 = b2f(q[base+32]);
  q[base]    = f2b(q1*cs - q2*sn);
  q[base+32] = f2b(q2*cs + q1*sn);
  float k1 = b2f(k[base]), k2 = b2f(k[base+32]);
  k[base]    = f2b(k1*cs - k2*sn);
  k[base+32] = f2b(k2*cs + k1*sn);
}

// ---------------- MFMA flash attention ----------------
// Block: 4 waves; wave w handles q rows [qblk*64 + w*16, +16) of head (b,h).
// KV tile = 64. Swapped QK^T (mfma(K,Q)) -> lane-local softmax rows.
// V staged in 4x16-subtiled LDS for ds_read_b64_tr_b16 PV A-fragments.
__global__ __launch_bounds__(256) void attn_mfma(
    const unsigned short* __restrict__ q, const unsigned short* __restrict__ k,
    const unsigned short* __restrict__ v, unsigned short* __restrict__ ao)
{
  __shared__ __align__(16) char lds[24576];
  char* Klds = lds;            // 8KB: [kv][dchunk^ (kv&7)] 16B chunks
  char* Vlds = lds + 8192;     // 8KB: subtiled [a=kv>>2][b=d>>4][r=kv&3][c=d&15]
  char* Plds = lds + 16384;    // 8KB: 4 waves x [q16][kv64] bf16, XOR-swizzled

  const int t = threadIdx.x;
  const int lane = t & 63, w = t >> 6;
  const int p15 = lane & 15, g = lane >> 4;
  const int bh = blockIdx.x >> 4;
  const int qblk = blockIdx.x & 15;
  const int b = bh >> 4, h = bh & 15;
  const size_t hoff = (size_t)h*HDz;
  const int q0 = qblk*64 + w*16;

  // Q B-fragments (col=q=p15, k=d=8g+j)
  const size_t qrow = (size_t)(b*Sz + q0 + p15)*Dz + hoff;
  const bf16x8 qf0 = *(const bf16x8*)(q + qrow + 8*g);
  const bf16x8 qf1 = *(const bf16x8*)(q + qrow + 32 + 8*g);

  char* Pw = Plds + w*2048;

  float mrun = -INFINITY, lsum = 0.f;
  f32x4 acc_o[4] = {};   // acc_o[bb][r] = O[q=p15][d=16bb+4g+r]

  const unsigned short* kbh = k + (size_t)(b*Sz)*Dz + hoff;
  const unsigned short* vbh = v + (size_t)(b*Sz)*Dz + hoff;

  for (int t0 = 0; t0 < Sz; t0 += 64) {
    __syncthreads();
    #pragma unroll
    for (int u = 0; u < 2; ++u) {
      int j = t + 256*u;
      int kkv = j >> 3, kdc = (j & 7) ^ (kkv & 7);
      gload16(kbh + (size_t)(t0 + kkv)*Dz + 8*kdc, Klds + j*16);
      int va = j >> 5, vbb = (j >> 3) & 3, vr = (j >> 1) & 3, vc = 8*(j & 1);
      gload16(vbh + (size_t)(t0 + 4*va + vr)*Dz + 16*vbb + vc, Vlds + j*16);
    }
    __syncthreads();

    // S^T tiles: sc[mt][r] = S[kv=mt*16+4g+r][q=p15] (pre-scale)
    f32x4 sc[4];
    #pragma unroll
    for (int mt = 0; mt < 4; ++mt) {
      int kv = mt*16 + p15;
      bf16x8 a0 = *(const bf16x8*)(Klds + kv*128 + ((g     ^ (kv & 7))*16));
      bf16x8 a1 = *(const bf16x8*)(Klds + kv*128 + (((g+4) ^ (kv & 7))*16));
      f32x4 z = {};
      z = __builtin_amdgcn_mfma_f32_16x16x32_bf16(a0, qf0, z, 0, 0, 0);
      z = __builtin_amdgcn_mfma_f32_16x16x32_bf16(a1, qf1, z, 0, 0, 0);
      sc[mt] = z;
    }

    // online softmax (row = q = p15, 16 lane-local + reduce over g groups)
    float pmax = -INFINITY;
    #pragma unroll
    for (int mt = 0; mt < 4; ++mt)
      #pragma unroll
      for (int r = 0; r < 4; ++r) {
        sc[mt][r] *= 0.125f;
        pmax = fmaxf(pmax, sc[mt][r]);
      }
    pmax = fmaxf(pmax, __shfl_xor(pmax, 16));
    pmax = fmaxf(pmax, __shfl_xor(pmax, 32));
    float mnew = fmaxf(mrun, pmax);
    float resc = __expf(mrun - mnew);
    mrun = mnew;
    float ps = 0.f;
    #pragma unroll
    for (int mt = 0; mt < 4; ++mt) {
      float p0 = __expf(sc[mt][0] - mnew);
      float p1 = __expf(sc[mt][1] - mnew);
      float p2 = __expf(sc[mt][2] - mnew);
      float p3 = __expf(sc[mt][3] - mnew);
      ps += (p0 + p1) + (p2 + p3);
      ushort4 pk;
      pk.x = f2b(p0); pk.y = f2b(p1); pk.z = f2b(p2); pk.w = f2b(p3);
      // byte addr: q*128 + kv*2 (kv = mt*16+4g) with XOR ((q&7)<<4)
      *(ushort4*)(Pw + ((p15*128 + mt*32 + g*8) ^ ((p15 & 7) << 4))) = pk;
    }
    ps += __shfl_xor(ps, 16);
    ps += __shfl_xor(ps, 32);
    lsum = lsum*resc + ps;
    #pragma unroll
    for (int bb = 0; bb < 4; ++bb) {
      acc_o[bb][0] *= resc; acc_o[bb][1] *= resc;
      acc_o[bb][2] *= resc; acc_o[bb][3] *= resc;
    }

    // PV: O^T[d][q] += V^T frag (tr-read) x P^T frag (LDS)
    #pragma unroll
    for (int bb = 0; bb < 4; ++bb) {
      #pragma unroll
      for (int kh = 0; kh < 2; ++kh) {
        const __attribute__((address_space(3))) char* vp =
          (const __attribute__((address_space(3))) char*)
            (Vlds + 4096*kh + 1024*g + 128*bb + 8*p15);
        bf16x4 v0, v1;
        asm volatile("ds_read_b64_tr_b16 %0, %2\n\t"
                     "ds_read_b64_tr_b16 %1, %2 offset:512\n\t"
                     "s_waitcnt lgkmcnt(0)"
                     : "=v"(v0), "=v"(v1) : "v"(vp) : "memory");
        __builtin_amdgcn_sched_barrier(0);
        union { bf16x4 h[2]; bf16x8 full; } af;
        af.h[0] = v0; af.h[1] = v1;
        bf16x8 pf = *(const bf16x8*)(Pw + ((p15*128 + kh*64 + g*16) ^ ((p15 & 7) << 4)));
        acc_o[bb] = __builtin_amdgcn_mfma_f32_16x16x32_bf16(af.full, pf, acc_o[bb], 0, 0, 0);
      }
    }
  }

  const float inv = 1.0f / lsum;
  const size_t orow = (size_t)(b*Sz + q0 + p15)*Dz + hoff;
  #pragma unroll
  for (int bb = 0; bb < 4; ++bb) {
    ushort4 o;
    o.x = f2b(acc_o[bb][0]*inv);
    o.y = f2b(acc_o[bb][1]*inv);
    o.z = f2b(acc_o[bb][2]*inv);
    o.w = f2b(acc_o[bb][3]*inv);
    *(ushort4*)(ao + orow + 16*bb + 4*g) = o;
  }
}

// ---------------- LayerNorm 1: out fp32 + bf16 ----------------
__global__ __launch_bounds__(256) void ln1_k(
    const float* __restrict__ a, const float* __restrict__ g,
    const float* __restrict__ beta, float* __restrict__ outf,
    unsigned short* __restrict__ outb)
{
  int n = blockIdx.x, t = threadIdx.x;
  __shared__ float red[256];
  float vals[4]; float s = 0.f;
  #pragma unroll
  for (int i = 0; i < 4; ++i) {
    int d = t + i*256;
    float x = a[(size_t)n*Dz + d];
    vals[i] = x; s += x;
  }
  red[t] = s; __syncthreads();
  for (int st = 128; st; st >>= 1) { if (t < st) red[t] += red[t+st]; __syncthreads(); }
  float mean = red[0] * (1.0f/Dz);
  __syncthreads();
  float vsum = 0.f;
  #pragma unroll
  for (int i = 0; i < 4; ++i){ float dd = vals[i]-mean; vsum += dd*dd; }
  red[t] = vsum; __syncthreads();
  for (int st = 128; st; st >>= 1) { if (t < st) red[t] += red[t+st]; __syncthreads(); }
  float rs = rsqrtf(red[0]*(1.0f/Dz) + EPSz);
  #pragma unroll
  for (int i = 0; i < 4; ++i) {
    int d = t + i*256;
    float o = (vals[i]-mean)*rs*g[d] + beta[d];
    outf[(size_t)n*Dz + d] = o;
    outb[(size_t)n*Dz + d] = f2b(o);
  }
}

// ---------------- gate ----------------
__global__ __launch_bounds__(64) void gate_topk(
    const float* __restrict__ x1, const float* __restrict__ Wg,
    const float* __restrict__ bg, int* __restrict__ counts,
    int* __restrict__ toklist, int4* __restrict__ tokinfo,
    float2* __restrict__ tokw)
{
  int n = blockIdx.x, lane = threadIdx.x;
  const float* row = x1 + (size_t)n*Dz;
  float acc[8] = {0,0,0,0,0,0,0,0};
  for (int d = lane; d < Dz; d += 64) {
    float xv = row[d];
    const float4* wp = (const float4*)(Wg + (size_t)d*Ez);
    float4 w0 = wp[0], w1 = wp[1];
    acc[0] += xv*w0.x; acc[1] += xv*w0.y; acc[2] += xv*w0.z; acc[3] += xv*w0.w;
    acc[4] += xv*w1.x; acc[5] += xv*w1.y; acc[6] += xv*w1.z; acc[7] += xv*w1.w;
  }
  #pragma unroll
  for (int e = 0; e < 8; ++e)
    #pragma unroll
    for (int off = 32; off; off >>= 1) acc[e] += __shfl_xor(acc[e], off);
  if (lane == 0) {
    float lg[8]; float mx = -INFINITY;
    #pragma unroll
    for (int e = 0; e < 8; ++e){ lg[e] = acc[e] + bg[e]; mx = fmaxf(mx, lg[e]); }
    float p[8];
    #pragma unroll
    for (int e = 0; e < 8; ++e) p[e] = __expf(lg[e]-mx);
    int e1 = 0; float m1 = p[0];
    for (int e = 1; e < 8; ++e) if (p[e] > m1){ m1 = p[e]; e1 = e; }
    int e2 = -1; float m2 = -INFINITY;
    for (int e = 0; e < 8; ++e) if (e != e1 && p[e] > m2){ m2 = p[e]; e2 = e; }
    float inv = 1.0f/(m1+m2);
    int p1 = atomicAdd(&counts[e1], 1); toklist[e1*Nz + p1] = n;
    int p2 = atomicAdd(&counts[e2], 1); toklist[e2*Nz + p2] = n;
    tokinfo[n] = make_int4(e1, p1, e2, p2);
    tokw[n] = make_float2(m1*inv, m2*inv);
  }
}

__global__ void prefix_k(const int* __restrict__ counts, int* __restrict__ offs){
  if (threadIdx.x == 0 && blockIdx.x == 0) {
    int s = 0;
    for (int e = 0; e < Ez; ++e){ offs[e] = s; s += counts[e]; }
    offs[Ez] = s;
  }
}

// ---------------- final combine + LayerNorm ----------------
__global__ __launch_bounds__(256) void ln2_k(
    const float* __restrict__ x1, const float* __restrict__ y,
    const int4* __restrict__ tokinfo, const float2* __restrict__ tokw,
    const int* __restrict__ offs, const float* __restrict__ g,
    const float* __restrict__ beta, float* __restrict__ out)
{
  int n = blockIdx.x, t = threadIdx.x;
  __shared__ float red[256];
  int4 ti = tokinfo[n]; float2 tw = tokw[n];
  const float* y1 = y + (size_t)(offs[ti.x] + ti.y)*Dz;
  const float* y2 = y + (size_t)(offs[ti.z] + ti.w)*Dz;
  float vals[4]; float s = 0.f;
  #pragma unroll
  for (int i = 0; i < 4; ++i) {
    int d = t + i*256;
    float x = x1[(size_t)n*Dz + d] + tw.x*y1[d] + tw.y*y2[d];
    vals[i] = x; s += x;
  }
  red[t] = s; __syncthreads();
  for (int st = 128; st; st >>= 1) { if (t < st) red[t] += red[t+st]; __syncthreads(); }
  float mean = red[0] * (1.0f/Dz);
  __syncthreads();
  float vsum = 0.f;
  #pragma unroll
  for (int i = 0; i < 4; ++i){ float dd = vals[i]-mean; vsum += dd*dd; }
  red[t] = vsum; __syncthreads();
  for (int st = 128; st; st >>= 1) { if (t < st) red[t] += red[t+st]; __syncthreads(); }
  float rs = rsqrtf(red[0]*(1.0f/Dz) + EPSz);
  #pragma unroll
  for (int i = 0; i < 4; ++i) {
    int d = t + i*256;
    out[(size_t)n*Dz + d] = (vals[i]-mean)*rs*g[d] + beta[d];
  }
}

extern "C" void kernel_launch(void* const* d_in, const int* in_sizes, int n_in,
                              void* d_out, int out_size, void* d_ws, size_t ws_size,
                              hipStream_t stream)
{
  const float* x  = (const float*)d_in[0];
  const float* Wq = (const float*)d_in[1];
  const float* bq = (const float*)d_in[2];
  const float* Wk = (const float*)d_in[3];
  const float* bk = (const float*)d_in[4];
  const float* Wv = (const float*)d_in[5];
  const float* bv = (const float*)d_in[6];
  const float* Wo = (const float*)d_in[7];
  const float* bo = (const float*)d_in[8];
  const float* Wg = (const float*)d_in[9];
  const float* bg = (const float*)d_in[10];
  const float* W1 = (const float*)d_in[11];
  const float* b1 = (const float*)d_in[12];
  const float* W2 = (const float*)d_in[13];
  const float* b2 = (const float*)d_in[14];
  const float* g1 = (const float*)d_in[15];
  const float* be1= (const float*)d_in[16];
  const float* g2 = (const float*)d_in[17];
  const float* be2= (const float*)d_in[18];
  float* out = (float*)d_out;

  const size_t PD = (size_t)Dz*Dz;
  const size_t ND = (size_t)Nz*Dz;
  unsigned short* Wqt = (unsigned short*)d_ws;
  unsigned short* Wkt = Wqt + PD;
  unsigned short* Wvt = Wkt + PD;
  unsigned short* Wot = Wvt + PD;
  unsigned short* W1t = Wot + PD;
  unsigned short* W2t = W1t + (size_t)Ez*FFz*Dz;
  unsigned short* hb  = W2t + (size_t)Ez*FFz*Dz;
  unsigned short* xb  = hb  + (size_t)2*Nz*FFz;
  unsigned short* qb  = xb  + ND;
  unsigned short* kb  = qb  + ND;
  unsigned short* vb  = kb  + ND;
  unsigned short* aob = vb  + ND;
  unsigned short* x1b = aob + ND;
  float* x1 = (float*)(x1b + ND);
  float* y  = x1 + ND;
  float* t1 = y;
  int4*  tokinfo = (int4*)(y + (size_t)2*Nz*Dz);
  float2* tokw   = (float2*)(tokinfo + Nz);
  int* counts  = (int*)(tokw + Nz);
  int* offs    = counts + Ez;
  int* toklist = offs + Ez + 1;

  dim3 blk(256);
  transpose_cvt<<<dim3(32,32,1), blk, 0, stream>>>(Wq, Wqt, Dz, Dz);
  transpose_cvt<<<dim3(32,32,1), blk, 0, stream>>>(Wk, Wkt, Dz, Dz);
  transpose_cvt<<<dim3(32,32,1), blk, 0, stream>>>(Wv, Wvt, Dz, Dz);
  transpose_cvt<<<dim3(32,32,1), blk, 0, stream>>>(Wo, Wot, Dz, Dz);
  transpose_cvt<<<dim3(FFz/32, Dz/32, Ez), blk, 0, stream>>>(W1, W1t, Dz, FFz);
  transpose_cvt<<<dim3(Dz/32, FFz/32, Ez), blk, 0, stream>>>(W2, W2t, FFz, Dz);
  cvt_bf16<<<(int)(ND/4/256), blk, 0, stream>>>(x, xb, (int)ND);

  gemm_proj<<<dim3(Dz/128, Nz/128), blk, 0, stream>>>(xb, Wqt, bq, nullptr, nullptr, qb, Nz, Dz, Dz);
  gemm_proj<<<dim3(Dz/128, Nz/128), blk, 0, stream>>>(xb, Wkt, bk, nullptr, nullptr, kb, Nz, Dz, Dz);
  gemm_proj<<<dim3(Dz/128, Nz/128), blk, 0, stream>>>(xb, Wvt, bv, nullptr, nullptr, vb, Nz, Dz, Dz);
  rope_qk<<<(Nz*Hz*32)/256, blk, 0, stream>>>(qb, kb);
  attn_mfma<<<dim3(Bz*Hz*(Sz/64)), blk, 0, stream>>>(qb, kb, vb, aob);
  gemm_proj<<<dim3(Dz/128, Nz/128), blk, 0, stream>>>(aob, Wot, bo, x, t1, nullptr, Nz, Dz, Dz);
  ln1_k<<<Nz, blk, 0, stream>>>(t1, g1, be1, x1, x1b);

  hipMemsetAsync(counts, 0, Ez*sizeof(int), stream);
  gate_topk<<<Nz, dim3(64), 0, stream>>>(x1, Wg, bg, counts, toklist, tokinfo, tokw);
  prefix_k<<<1, dim3(64), 0, stream>>>(counts, offs);
  moe_gemm1<<<dim3(FFz/128, Nz/128, Ez), blk, 0, stream>>>(x1b, W1t, b1, counts, offs, toklist, hb);
  moe_gemm2<<<dim3(Dz/128, Nz/128, Ez), blk, 0, stream>>>(hb, W2t, b2, counts, offs, y);
  ln2_k<<<Nz, blk, 0, stream>>>(x1, y, tokinfo, tokw, offs, g2, be2, out);
}

// Round 4
// 560.999 us; speedup vs baseline: 6.0215x; 1.2964x over previous
//
#include <hip/hip_runtime.h>
#include <cmath>

#define Bz 2
#define Sz 1024
#define Dz 1024
#define Hz 16
#define HDz 64
#define Ez 8
#define FFz 4096
#define Nz (Bz*Sz)
#define QKVSz (3*Dz)
#define EPSz 1e-5f

typedef __attribute__((ext_vector_type(8))) short bf16x8;
typedef __attribute__((ext_vector_type(4))) short bf16x4;
typedef __attribute__((ext_vector_type(4))) float f32x4;
typedef __attribute__((ext_vector_type(8))) unsigned short ushortx8;

__device__ __forceinline__ float b2f(unsigned short u){
  union { unsigned int i; float f; } x; x.i = ((unsigned int)u) << 16; return x.f;
}
__device__ __forceinline__ unsigned short f2b(float f){
  union { float f; unsigned int i; } x; x.f = f;
  unsigned int r = x.i + 0x7FFFu + ((x.i >> 16) & 1u);
  return (unsigned short)(r >> 16);
}
__device__ __forceinline__ float gelu_f(float x){
  return 0.5f*x*(1.0f + erff(x*0.70710678118654752f));
}
__device__ __forceinline__ void gload16(const void* g, void* l){
  __builtin_amdgcn_global_load_lds(
    (const __attribute__((address_space(1))) unsigned int*)g,
    (__attribute__((address_space(3))) unsigned int*)l, 16, 0, 0);
}

// ---------------- fp32 -> bf16 plain convert ----------------
__global__ __launch_bounds__(256) void cvt_bf16(
    const float* __restrict__ in, unsigned short* __restrict__ out, int n)
{
  int i = (blockIdx.x*blockDim.x + threadIdx.x)*4;
  if (i >= n) return;
  float4 v = *(const float4*)(in + i);
  ushort4 o;
  o.x = f2b(v.x); o.y = f2b(v.y); o.z = f2b(v.z); o.w = f2b(v.w);
  *(ushort4*)(out + i) = o;
}

// ---------------- fp32 [z][R][C] -> bf16 [z][C][R] ----------------
__global__ __launch_bounds__(256) void transpose_cvt(
    const float* __restrict__ in, unsigned short* __restrict__ out, int R, int C)
{
  __shared__ float tile[32][33];
  const size_t boff = (size_t)blockIdx.z * R * C;
  int c0 = blockIdx.x*32, r0 = blockIdx.y*32;
  int tx = threadIdx.x & 31, ty = threadIdx.x >> 5;
  #pragma unroll
  for (int i = 0; i < 4; ++i)
    tile[ty + 8*i][tx] = in[boff + (size_t)(r0+ty+8*i)*C + c0 + tx];
  __syncthreads();
  #pragma unroll
  for (int i = 0; i < 4; ++i)
    out[boff + (size_t)(c0+ty+8*i)*R + r0 + tx] = f2b(tile[tx][ty+8*i]);
}

// ---------------- bias concat (bq|bk|bv) ----------------
__global__ void concat3(const float* __restrict__ a, const float* __restrict__ b,
                        const float* __restrict__ c, float* __restrict__ o)
{
  int i = blockIdx.x*256 + threadIdx.x;
  if (i >= 3072) return;
  o[i] = (i < 1024) ? a[i] : (i < 2048 ? b[i-1024] : c[i-2048]);
}

// ---------------- t1 = x + bo ----------------
__global__ __launch_bounds__(256) void init_t1(
    const float* __restrict__ x, const float* __restrict__ bo, float* __restrict__ t1)
{
  int i = blockIdx.x*256 + threadIdx.x;   // float4 index
  float4 xv = ((const float4*)x)[i];
  float4 bv = ((const float4*)bo)[i & 255];
  xv.x += bv.x; xv.y += bv.y; xv.z += bv.z; xv.w += bv.w;
  ((float4*)t1)[i] = xv;
}

// ---------------- MFMA 128x128xK core (4 waves, 16x16x32 bf16) ----------------
__device__ __forceinline__ void mfma_kloop(
    const unsigned short* __restrict__ pA0, const unsigned short* __restrict__ pA1,
    const unsigned short* __restrict__ pB0, const unsigned short* __restrict__ pB1,
    char* lds, int t, int K, f32x4 acc[4][4])
{
  char* dA0 = lds + t*16;
  char* dA1 = lds + (256+t)*16;
  char* dB0 = lds + 8192 + t*16;
  char* dB1 = lds + 8192 + (256+t)*16;
  const int lane = t & 63, w = t >> 6;
  const int wr = (w >> 1) << 6, wc = (w & 1) << 6;
  const int iA = (lane >> 4)*128 + wr + (lane & 15);
  const int iB = (lane >> 4)*128 + wc + (lane & 15);
  const bf16x8* fA = (const bf16x8*)lds;
  const bf16x8* fB = (const bf16x8*)(lds + 8192);
  for (int k0 = 0; k0 < K; k0 += 32) {
    __syncthreads();
    gload16(pA0 + k0, dA0);
    gload16(pA1 + k0, dA1);
    gload16(pB0 + k0, dB0);
    gload16(pB1 + k0, dB1);
    __syncthreads();
    bf16x8 a[4], b[4];
    #pragma unroll
    for (int m = 0; m < 4; ++m) a[m] = fA[iA + m*16];
    #pragma unroll
    for (int n = 0; n < 4; ++n) b[n] = fB[iB + n*16];
    #pragma unroll
    for (int m = 0; m < 4; ++m)
      #pragma unroll
      for (int n = 0; n < 4; ++n)
        acc[m][n] = __builtin_amdgcn_mfma_f32_16x16x32_bf16(a[m], b[n], acc[m][n], 0, 0, 0);
  }
}

// ---------------- dense GEMM with optional split-K ----------------
// mode 0: outb = f2b(acc + bias[col]); mode 2: atomicAdd(outf, acc)
__global__ __launch_bounds__(256) void gemm_proj(
    const unsigned short* __restrict__ A, const unsigned short* __restrict__ Bt,
    const float* __restrict__ bias, float* __restrict__ outf,
    unsigned short* __restrict__ outb, int M, int Nn, int K, int KS, int mode)
{
  __shared__ __align__(16) char lds[16384];
  const int t = threadIdx.x;
  const int nblk = Nn >> 7;
  const int chunk = blockIdx.x / nblk;
  const int n0 = (blockIdx.x - chunk*nblk) << 7;
  const int m0 = blockIdx.y << 7;
  const int Kc = K / KS;
  const int kbase = chunk * Kc;
  const int ridx = t & 127, kc = t >> 7;
  const unsigned short* pA0 = A + (size_t)(m0 + ridx)*K + kbase + kc*8;
  const unsigned short* pB0 = Bt + (size_t)(n0 + ridx)*K + kbase + kc*8;
  f32x4 acc[4][4] = {};
  mfma_kloop(pA0, pA0+16, pB0, pB0+16, lds, t, Kc, acc);
  const int lane = t & 63, w = t >> 6;
  const int wr = (w>>1)<<6, wc = (w&1)<<6, lq = lane>>4, lr = lane&15;
  #pragma unroll
  for (int m = 0; m < 4; ++m)
    #pragma unroll
    for (int r = 0; r < 4; ++r) {
      int row = m0 + wr + m*16 + lq*4 + r;
      #pragma unroll
      for (int n = 0; n < 4; ++n) {
        int col = n0 + wc + n*16 + lr;
        if (mode == 0) outb[(size_t)row*Nn + col] = f2b(acc[m][n][r] + bias[col]);
        else atomicAdd(&outf[(size_t)row*Nn + col], acc[m][n][r]);
      }
    }
}

// ---------------- grouped MoE GEMM1 ----------------
__global__ __launch_bounds__(256) void moe_gemm1(
    const unsigned short* __restrict__ x1b, const unsigned short* __restrict__ W1t,
    const float* __restrict__ b1, const int* __restrict__ counts,
    const int* __restrict__ offs, const int* __restrict__ toklist,
    unsigned short* __restrict__ hb)
{
  const int e = blockIdx.z, cnt = counts[e], r0 = blockIdx.y*128;
  if (r0 >= cnt) return;
  __shared__ __align__(16) char lds[16384];
  const int t = threadIdx.x, n0 = blockIdx.x*128;
  const int ridx = t & 127, kc = t >> 7;
  const int rg = r0 + ridx;
  const int tok = toklist[e*Nz + (rg < cnt ? rg : 0)];
  const unsigned short* pA0 = x1b + (size_t)tok*Dz + kc*8;
  const unsigned short* pB0 = W1t + ((size_t)e*FFz + n0 + ridx)*Dz + kc*8;
  f32x4 acc[4][4] = {};
  mfma_kloop(pA0, pA0+16, pB0, pB0+16, lds, t, Dz, acc);
  const int lane = t & 63, w = t >> 6;
  const int wr = (w>>1)<<6, wc = (w&1)<<6, lq = lane>>4, lr = lane&15;
  const int base = offs[e] + r0;
  #pragma unroll
  for (int m = 0; m < 4; ++m)
    #pragma unroll
    for (int r = 0; r < 4; ++r) {
      int row = wr + m*16 + lq*4 + r;
      if (r0 + row >= cnt) continue;
      #pragma unroll
      for (int n = 0; n < 4; ++n) {
        int col = n0 + wc + n*16 + lr;
        hb[(size_t)(base+row)*FFz + col] = f2b(gelu_f(acc[m][n][r] + b1[e*FFz + col]));
      }
    }
}

// ---------------- grouped MoE GEMM2, split-K x4, atomic fp32 ----------------
__global__ __launch_bounds__(256) void moe_gemm2(
    const unsigned short* __restrict__ hb, const unsigned short* __restrict__ W2t,
    const int* __restrict__ counts, const int* __restrict__ offs,
    float* __restrict__ y)
{
  const int e = blockIdx.z, cnt = counts[e], r0 = blockIdx.y*128;
  if (r0 >= cnt) return;
  __shared__ __align__(16) char lds[16384];
  const int t = threadIdx.x;
  const int chunk = blockIdx.x >> 3;
  const int n0 = (blockIdx.x & 7) << 7;
  const int kbase = chunk * (FFz/4);
  const int ridx = t & 127, kc = t >> 7;
  const int rg = r0 + ridx;
  const int slot = offs[e] + (rg < cnt ? rg : 0);
  const unsigned short* pA0 = hb + (size_t)slot*FFz + kbase + kc*8;
  const unsigned short* pB0 = W2t + ((size_t)e*Dz + n0 + ridx)*FFz + kbase + kc*8;
  f32x4 acc[4][4] = {};
  mfma_kloop(pA0, pA0+16, pB0, pB0+16, lds, t, FFz/4, acc);
  const int lane = t & 63, w = t >> 6;
  const int wr = (w>>1)<<6, wc = (w&1)<<6, lq = lane>>4, lr = lane&15;
  const int base = offs[e] + r0;
  #pragma unroll
  for (int m = 0; m < 4; ++m)
    #pragma unroll
    for (int r = 0; r < 4; ++r) {
      int row = wr + m*16 + lq*4 + r;
      if (r0 + row >= cnt) continue;
      #pragma unroll
      for (int n = 0; n < 4; ++n) {
        int col = n0 + wc + n*16 + lr;
        atomicAdd(&y[(size_t)(base+row)*Dz + col], acc[m][n][r]);
      }
    }
}

// ---------------- RoPE (in-place on fused qkv buffer) ----------------
__global__ void rope_qk(unsigned short* __restrict__ qkv){
  int gid = blockIdx.x*blockDim.x + threadIdx.x;
  int i = gid & 31;
  int h = (gid >> 5) & (Hz-1);
  int n = gid >> 9;
  int s = n & (Sz-1);
  float inv = powf(10000.0f, -(float)(2*i)/64.0f);
  float ang = (float)s * inv;
  float cs = cosf(ang), sn = sinf(ang);
  size_t base = (size_t)n*QKVSz + h*HDz + i;
  float q1 = b2f(qkv[base]), q2 = b2f(qkv[base+32]);
  qkv[base]    = f2b(q1*cs - q2*sn);
  qkv[base+32] = f2b(q2*cs + q1*sn);
  float k1 = b2f(qkv[base+Dz]), k2 = b2f(qkv[base+Dz+32]);
  qkv[base+Dz]    = f2b(k1*cs - k2*sn);
  qkv[base+Dz+32] = f2b(k2*cs + k1*sn);
}

// ---------------- MFMA flash attention (q/k/v strided QKVSz) ----------------
__global__ __launch_bounds__(256) void attn_mfma(
    const unsigned short* __restrict__ q, const unsigned short* __restrict__ k,
    const unsigned short* __restrict__ v, unsigned short* __restrict__ ao)
{
  __shared__ __align__(16) char lds[24576];
  char* Klds = lds;
  char* Vlds = lds + 8192;
  char* Plds = lds + 16384;

  const int t = threadIdx.x;
  const int lane = t & 63, w = t >> 6;
  const int p15 = lane & 15, g = lane >> 4;
  const int bh = blockIdx.x >> 4;
  const int qblk = blockIdx.x & 15;
  const int b = bh >> 4, h = bh & 15;
  const size_t hoff = (size_t)h*HDz;
  const int q0 = qblk*64 + w*16;

  const size_t qrow = (size_t)(b*Sz + q0 + p15)*QKVSz + hoff;
  const bf16x8 qf0 = *(const bf16x8*)(q + qrow + 8*g);
  const bf16x8 qf1 = *(const bf16x8*)(q + qrow + 32 + 8*g);

  char* Pw = Plds + w*2048;

  float mrun = -INFINITY, lsum = 0.f;
  f32x4 acc_o[4] = {};

  const unsigned short* kbh = k + (size_t)(b*Sz)*QKVSz + hoff;
  const unsigned short* vbh = v + (size_t)(b*Sz)*QKVSz + hoff;

  for (int t0 = 0; t0 < Sz; t0 += 64) {
    __syncthreads();
    #pragma unroll
    for (int u = 0; u < 2; ++u) {
      int j = t + 256*u;
      int kkv = j >> 3, kdc = (j & 7) ^ (kkv & 7);
      gload16(kbh + (size_t)(t0 + kkv)*QKVSz + 8*kdc, Klds + j*16);
      int va = j >> 5, vbb = (j >> 3) & 3, vr = (j >> 1) & 3, vc = 8*(j & 1);
      gload16(vbh + (size_t)(t0 + 4*va + vr)*QKVSz + 16*vbb + vc, Vlds + j*16);
    }
    __syncthreads();

    f32x4 sc[4];
    #pragma unroll
    for (int mt = 0; mt < 4; ++mt) {
      int kv = mt*16 + p15;
      bf16x8 a0 = *(const bf16x8*)(Klds + kv*128 + ((g     ^ (kv & 7))*16));
      bf16x8 a1 = *(const bf16x8*)(Klds + kv*128 + (((g+4) ^ (kv & 7))*16));
      f32x4 z = {};
      z = __builtin_amdgcn_mfma_f32_16x16x32_bf16(a0, qf0, z, 0, 0, 0);
      z = __builtin_amdgcn_mfma_f32_16x16x32_bf16(a1, qf1, z, 0, 0, 0);
      sc[mt] = z;
    }

    float pmax = -INFINITY;
    #pragma unroll
    for (int mt = 0; mt < 4; ++mt)
      #pragma unroll
      for (int r = 0; r < 4; ++r) {
        sc[mt][r] *= 0.125f;
        pmax = fmaxf(pmax, sc[mt][r]);
      }
    pmax = fmaxf(pmax, __shfl_xor(pmax, 16));
    pmax = fmaxf(pmax, __shfl_xor(pmax, 32));
    float mnew = fmaxf(mrun, pmax);
    float resc = __expf(mrun - mnew);
    mrun = mnew;
    float ps = 0.f;
    #pragma unroll
    for (int mt = 0; mt < 4; ++mt) {
      float p0 = __expf(sc[mt][0] - mnew);
      float p1 = __expf(sc[mt][1] - mnew);
      float p2 = __expf(sc[mt][2] - mnew);
      float p3 = __expf(sc[mt][3] - mnew);
      ps += (p0 + p1) + (p2 + p3);
      ushort4 pk;
      pk.x = f2b(p0); pk.y = f2b(p1); pk.z = f2b(p2); pk.w = f2b(p3);
      *(ushort4*)(Pw + ((p15*128 + mt*32 + g*8) ^ ((p15 & 7) << 4))) = pk;
    }
    ps += __shfl_xor(ps, 16);
    ps += __shfl_xor(ps, 32);
    lsum = lsum*resc + ps;
    #pragma unroll
    for (int bb = 0; bb < 4; ++bb) {
      acc_o[bb][0] *= resc; acc_o[bb][1] *= resc;
      acc_o[bb][2] *= resc; acc_o[bb][3] *= resc;
    }

    #pragma unroll
    for (int bb = 0; bb < 4; ++bb) {
      #pragma unroll
      for (int kh = 0; kh < 2; ++kh) {
        const __attribute__((address_space(3))) char* vp =
          (const __attribute__((address_space(3))) char*)
            (Vlds + 4096*kh + 1024*g + 128*bb + 8*p15);
        bf16x4 v0, v1;
        asm volatile("ds_read_b64_tr_b16 %0, %2\n\t"
                     "ds_read_b64_tr_b16 %1, %2 offset:512\n\t"
                     "s_waitcnt lgkmcnt(0)"
                     : "=v"(v0), "=v"(v1) : "v"(vp) : "memory");
        __builtin_amdgcn_sched_barrier(0);
        union { bf16x4 hh[2]; bf16x8 full; } af;
        af.hh[0] = v0; af.hh[1] = v1;
        bf16x8 pf = *(const bf16x8*)(Pw + ((p15*128 + kh*64 + g*16) ^ ((p15 & 7) << 4)));
        acc_o[bb] = __builtin_amdgcn_mfma_f32_16x16x32_bf16(af.full, pf, acc_o[bb], 0, 0, 0);
      }
    }
  }

  const float inv = 1.0f / lsum;
  const size_t orow = (size_t)(b*Sz + q0 + p15)*Dz + hoff;
  #pragma unroll
  for (int bb = 0; bb < 4; ++bb) {
    ushort4 o;
    o.x = f2b(acc_o[bb][0]*inv);
    o.y = f2b(acc_o[bb][1]*inv);
    o.z = f2b(acc_o[bb][2]*inv);
    o.w = f2b(acc_o[bb][3]*inv);
    *(ushort4*)(ao + orow + 16*bb + 4*g) = o;
  }
}

// ---------------- LayerNorm 1 ----------------
__global__ __launch_bounds__(256) void ln1_k(
    const float* __restrict__ a, const float* __restrict__ g,
    const float* __restrict__ beta, float* __restrict__ outf,
    unsigned short* __restrict__ outb)
{
  int n = blockIdx.x, t = threadIdx.x;
  __shared__ float red[256];
  float vals[4]; float s = 0.f;
  #pragma unroll
  for (int i = 0; i < 4; ++i) {
    int d = t + i*256;
    float x = a[(size_t)n*Dz + d];
    vals[i] = x; s += x;
  }
  red[t] = s; __syncthreads();
  for (int st = 128; st; st >>= 1) { if (t < st) red[t] += red[t+st]; __syncthreads(); }
  float mean = red[0] * (1.0f/Dz);
  __syncthreads();
  float vsum = 0.f;
  #pragma unroll
  for (int i = 0; i < 4; ++i){ float dd = vals[i]-mean; vsum += dd*dd; }
  red[t] = vsum; __syncthreads();
  for (int st = 128; st; st >>= 1) { if (t < st) red[t] += red[t+st]; __syncthreads(); }
  float rs = rsqrtf(red[0]*(1.0f/Dz) + EPSz);
  #pragma unroll
  for (int i = 0; i < 4; ++i) {
    int d = t + i*256;
    float o = (vals[i]-mean)*rs*g[d] + beta[d];
    outf[(size_t)n*Dz + d] = o;
    outb[(size_t)n*Dz + d] = f2b(o);
  }
}

// ---------------- gate ----------------
__global__ __launch_bounds__(64) void gate_topk(
    const float* __restrict__ x1, const float* __restrict__ Wg,
    const float* __restrict__ bg, int* __restrict__ counts,
    int* __restrict__ toklist, int4* __restrict__ tokinfo,
    float2* __restrict__ tokw)
{
  int n = blockIdx.x, lane = threadIdx.x;
  const float* row = x1 + (size_t)n*Dz;
  float acc[8] = {0,0,0,0,0,0,0,0};
  for (int d = lane; d < Dz; d += 64) {
    float xv = row[d];
    const float4* wp = (const float4*)(Wg + (size_t)d*Ez);
    float4 w0 = wp[0], w1 = wp[1];
    acc[0] += xv*w0.x; acc[1] += xv*w0.y; acc[2] += xv*w0.z; acc[3] += xv*w0.w;
    acc[4] += xv*w1.x; acc[5] += xv*w1.y; acc[6] += xv*w1.z; acc[7] += xv*w1.w;
  }
  #pragma unroll
  for (int e = 0; e < 8; ++e)
    #pragma unroll
    for (int off = 32; off; off >>= 1) acc[e] += __shfl_xor(acc[e], off);
  if (lane == 0) {
    float lg[8]; float mx = -INFINITY;
    #pragma unroll
    for (int e = 0; e < 8; ++e){ lg[e] = acc[e] + bg[e]; mx = fmaxf(mx, lg[e]); }
    float p[8];
    #pragma unroll
    for (int e = 0; e < 8; ++e) p[e] = __expf(lg[e]-mx);
    int e1 = 0; float m1 = p[0];
    for (int e = 1; e < 8; ++e) if (p[e] > m1){ m1 = p[e]; e1 = e; }
    int e2 = -1; float m2 = -INFINITY;
    for (int e = 0; e < 8; ++e) if (e != e1 && p[e] > m2){ m2 = p[e]; e2 = e; }
    float inv = 1.0f/(m1+m2);
    int p1 = atomicAdd(&counts[e1], 1); toklist[e1*Nz + p1] = n;
    int p2 = atomicAdd(&counts[e2], 1); toklist[e2*Nz + p2] = n;
    tokinfo[n] = make_int4(e1, p1, e2, p2);
    tokw[n] = make_float2(m1*inv, m2*inv);
  }
}

__global__ void prefix_k(const int* __restrict__ counts, int* __restrict__ offs){
  if (threadIdx.x == 0 && blockIdx.x == 0) {
    int s = 0;
    for (int e = 0; e < Ez; ++e){ offs[e] = s; s += counts[e]; }
    offs[Ez] = s;
  }
}

// ---------------- final combine + LayerNorm (b2 folded here) ----------------
__global__ __launch_bounds__(256) void ln2_k(
    const float* __restrict__ x1, const float* __restrict__ y,
    const float* __restrict__ b2, const int4* __restrict__ tokinfo,
    const float2* __restrict__ tokw, const int* __restrict__ offs,
    const float* __restrict__ g, const float* __restrict__ beta,
    float* __restrict__ out)
{
  int n = blockIdx.x, t = threadIdx.x;
  __shared__ float red[256];
  int4 ti = tokinfo[n]; float2 tw = tokw[n];
  const float* y1 = y + (size_t)(offs[ti.x] + ti.y)*Dz;
  const float* y2 = y + (size_t)(offs[ti.z] + ti.w)*Dz;
  const float* b2a = b2 + (size_t)ti.x*Dz;
  const float* b2b = b2 + (size_t)ti.z*Dz;
  float vals[4]; float s = 0.f;
  #pragma unroll
  for (int i = 0; i < 4; ++i) {
    int d = t + i*256;
    float x = x1[(size_t)n*Dz + d] + tw.x*(y1[d] + b2a[d]) + tw.y*(y2[d] + b2b[d]);
    vals[i] = x; s += x;
  }
  red[t] = s; __syncthreads();
  for (int st = 128; st; st >>= 1) { if (t < st) red[t] += red[t+st]; __syncthreads(); }
  float mean = red[0] * (1.0f/Dz);
  __syncthreads();
  float vsum = 0.f;
  #pragma unroll
  for (int i = 0; i < 4; ++i){ float dd = vals[i]-mean; vsum += dd*dd; }
  red[t] = vsum; __syncthreads();
  for (int st = 128; st; st >>= 1) { if (t < st) red[t] += red[t+st]; __syncthreads(); }
  float rs = rsqrtf(red[0]*(1.0f/Dz) + EPSz);
  #pragma unroll
  for (int i = 0; i < 4; ++i) {
    int d = t + i*256;
    out[(size_t)n*Dz + d] = (vals[i]-mean)*rs*g[d] + beta[d];
  }
}

extern "C" void kernel_launch(void* const* d_in, const int* in_sizes, int n_in,
                              void* d_out, int out_size, void* d_ws, size_t ws_size,
                              hipStream_t stream)
{
  const float* x  = (const float*)d_in[0];
  const float* Wq = (const float*)d_in[1];
  const float* bq = (const float*)d_in[2];
  const float* Wk = (const float*)d_in[3];
  const float* bk = (const float*)d_in[4];
  const float* Wv = (const float*)d_in[5];
  const float* bv = (const float*)d_in[6];
  const float* Wo = (const float*)d_in[7];
  const float* bo = (const float*)d_in[8];
  const float* Wg = (const float*)d_in[9];
  const float* bg = (const float*)d_in[10];
  const float* W1 = (const float*)d_in[11];
  const float* b1 = (const float*)d_in[12];
  const float* W2 = (const float*)d_in[13];
  const float* b2 = (const float*)d_in[14];
  const float* g1 = (const float*)d_in[15];
  const float* be1= (const float*)d_in[16];
  const float* g2 = (const float*)d_in[17];
  const float* be2= (const float*)d_in[18];
  float* out = (float*)d_out;

  const size_t PD = (size_t)Dz*Dz;
  const size_t ND = (size_t)Nz*Dz;
  unsigned short* Wqt = (unsigned short*)d_ws;   // [3072][1024] fused B
  unsigned short* Wkt = Wqt + PD;
  unsigned short* Wvt = Wkt + PD;
  unsigned short* Wot = Wvt + PD;
  unsigned short* W1t = Wot + PD;
  unsigned short* W2t = W1t + (size_t)Ez*FFz*Dz;
  unsigned short* hb  = W2t + (size_t)Ez*FFz*Dz;
  unsigned short* xb  = hb  + (size_t)2*Nz*FFz;
  unsigned short* qkvb= xb  + ND;                 // [Nz][3072]
  unsigned short* aob = qkvb + (size_t)Nz*QKVSz;
  unsigned short* x1b = aob + ND;
  float* x1 = (float*)(x1b + ND);
  float* t1 = x1 + ND;
  float* y  = t1 + ND;                            // [2*Nz][Dz]
  float* bqkv = y + (size_t)2*Nz*Dz;
  int4*  tokinfo = (int4*)(bqkv + QKVSz);
  float2* tokw   = (float2*)(tokinfo + Nz);
  int* counts  = (int*)(tokw + Nz);
  int* offs    = counts + Ez;
  int* toklist = offs + Ez + 1;

  dim3 blk(256);
  transpose_cvt<<<dim3(32,32,1), blk, 0, stream>>>(Wq, Wqt, Dz, Dz);
  transpose_cvt<<<dim3(32,32,1), blk, 0, stream>>>(Wk, Wkt, Dz, Dz);
  transpose_cvt<<<dim3(32,32,1), blk, 0, stream>>>(Wv, Wvt, Dz, Dz);
  transpose_cvt<<<dim3(32,32,1), blk, 0, stream>>>(Wo, Wot, Dz, Dz);
  transpose_cvt<<<dim3(FFz/32, Dz/32, Ez), blk, 0, stream>>>(W1, W1t, Dz, FFz);
  transpose_cvt<<<dim3(Dz/32, FFz/32, Ez), blk, 0, stream>>>(W2, W2t, FFz, Dz);
  concat3<<<12, blk, 0, stream>>>(bq, bk, bv, bqkv);
  cvt_bf16<<<(int)(ND/4/256), blk, 0, stream>>>(x, xb, (int)ND);

  // fused QKV: [2048,1024] @ [1024,3072] -> qkvb
  gemm_proj<<<dim3(QKVSz/128, Nz/128), blk, 0, stream>>>(
      xb, Wqt, bqkv, nullptr, qkvb, Nz, QKVSz, Dz, 1, 0);
  rope_qk<<<(Nz*Hz*32)/256, blk, 0, stream>>>(qkvb);
  attn_mfma<<<dim3(Bz*Hz*(Sz/64)), blk, 0, stream>>>(qkvb, qkvb + Dz, qkvb + 2*Dz, aob);

  // O projection: t1 = x + bo, then split-K x2 atomic accumulate
  init_t1<<<(int)(ND/4/256), blk, 0, stream>>>(x, bo, t1);
  gemm_proj<<<dim3((Dz/128)*2, Nz/128), blk, 0, stream>>>(
      aob, Wot, nullptr, t1, nullptr, Nz, Dz, Dz, 2, 2);
  ln1_k<<<Nz, blk, 0, stream>>>(t1, g1, be1, x1, x1b);

  hipMemsetAsync(counts, 0, Ez*sizeof(int), stream);
  hipMemsetAsync(y, 0, (size_t)2*Nz*Dz*sizeof(float), stream);
  gate_topk<<<Nz, dim3(64), 0, stream>>>(x1, Wg, bg, counts, toklist, tokinfo, tokw);
  prefix_k<<<1, dim3(64), 0, stream>>>(counts, offs);
  moe_gemm1<<<dim3(FFz/128, Nz/128, Ez), blk, 0, stream>>>(x1b, W1t, b1, counts, offs, toklist, hb);
  moe_gemm2<<<dim3((Dz/128)*4, Nz/128, Ez), blk, 0, stream>>>(hb, W2t, counts, offs, y);
  ln2_k<<<Nz, blk, 0, stream>>>(x1, y, b2, tokinfo, tokw, offs, g2, be2, out);
}

// Round 5
// 519.227 us; speedup vs baseline: 6.5059x; 1.0804x over previous
//
#include <hip/hip_runtime.h>
#include <cmath>

#define Bz 2
#define Sz 1024
#define Dz 1024
#define Hz 16
#define HDz 64
#define Ez 8
#define FFz 4096
#define Nz (Bz*Sz)
#define QKVSz (3*Dz)
#define EPSz 1e-5f
#define NRB 48

typedef __attribute__((ext_vector_type(8))) short bf16x8;
typedef __attribute__((ext_vector_type(4))) short bf16x4;
typedef __attribute__((ext_vector_type(4))) float f32x4;
typedef __attribute__((ext_vector_type(8))) unsigned short ushortx8;

__device__ __forceinline__ float b2f(unsigned short u){
  union { unsigned int i; float f; } x; x.i = ((unsigned int)u) << 16; return x.f;
}
__device__ __forceinline__ unsigned short f2b(float f){
  union { float f; unsigned int i; } x; x.f = f;
  unsigned int r = x.i + 0x7FFFu + ((x.i >> 16) & 1u);
  return (unsigned short)(r >> 16);
}
__device__ __forceinline__ float gelu_f(float x){
  return 0.5f*x*(1.0f + erff(x*0.70710678118654752f));
}
__device__ __forceinline__ void gload16(const void* g, void* l){
  __builtin_amdgcn_global_load_lds(
    (const __attribute__((address_space(1))) unsigned int*)g,
    (__attribute__((address_space(3))) unsigned int*)l, 16, 0, 0);
}

// ---------------- fp32 -> bf16 plain convert ----------------
__global__ __launch_bounds__(256) void cvt_bf16(
    const float* __restrict__ in, unsigned short* __restrict__ out, int n)
{
  int i = (blockIdx.x*blockDim.x + threadIdx.x)*4;
  if (i >= n) return;
  float4 v = *(const float4*)(in + i);
  ushort4 o;
  o.x = f2b(v.x); o.y = f2b(v.y); o.z = f2b(v.z); o.w = f2b(v.w);
  *(ushort4*)(out + i) = o;
}

// ---------------- fp32 [z][R][C] -> bf16 [z][C][R], 64x64 tiles ----------------
__global__ __launch_bounds__(256) void transpose_cvt(
    const float* __restrict__ in, unsigned short* __restrict__ out, int R, int C)
{
  __shared__ float tile[64][65];
  const size_t boff = (size_t)blockIdx.z * R * C;
  int c0 = blockIdx.x*64, r0 = blockIdx.y*64;
  int tx = threadIdx.x & 15, ty = threadIdx.x >> 4;   // 16x16
  #pragma unroll
  for (int i = 0; i < 4; ++i) {
    float4 v = *(const float4*)(in + boff + (size_t)(r0+ty+16*i)*C + c0 + tx*4);
    tile[ty+16*i][tx*4+0] = v.x; tile[ty+16*i][tx*4+1] = v.y;
    tile[ty+16*i][tx*4+2] = v.z; tile[ty+16*i][tx*4+3] = v.w;
  }
  __syncthreads();
  int oc = threadIdx.x >> 3;   // 0..31: out-row within pass
  int og = threadIdx.x & 7;    // 8 groups of 8 elems
  #pragma unroll
  for (int p = 0; p < 2; ++p) {
    int c = oc + p*32;
    ushortx8 u;
    #pragma unroll
    for (int j = 0; j < 8; ++j) u[j] = f2b(tile[og*8+j][c]);
    *(ushortx8*)(out + boff + (size_t)(c0+c)*R + r0 + og*8) = u;
  }
}

// ---------------- bias concat (bq|bk|bv) ----------------
__global__ void concat3(const float* __restrict__ a, const float* __restrict__ b,
                        const float* __restrict__ c, float* __restrict__ o)
{
  int i = blockIdx.x*256 + threadIdx.x;
  if (i >= 3072) return;
  o[i] = (i < 1024) ? a[i] : (i < 2048 ? b[i-1024] : c[i-2048]);
}

// ---------------- t1 = x + bo ----------------
__global__ __launch_bounds__(256) void init_t1(
    const float* __restrict__ x, const float* __restrict__ bo, float* __restrict__ t1)
{
  int i = blockIdx.x*256 + threadIdx.x;   // float4 index
  float4 xv = ((const float4*)x)[i];
  float4 bv = ((const float4*)bo)[i & 255];
  xv.x += bv.x; xv.y += bv.y; xv.z += bv.z; xv.w += bv.w;
  ((float4*)t1)[i] = xv;
}

// ------- MFMA 128x128xK core, 2-phase double-buffered prefetch -------
// LDS: 2 buffers x (A 8KB | B 8KB) = 32 KB. STAGE(next) issued before
// compute(cur); single __syncthreads (vmcnt0 drain) per K-step.
__device__ __forceinline__ void mfma_kloop(
    const unsigned short* __restrict__ pA0,
    const unsigned short* __restrict__ pB0,
    char* lds, int t, int K, f32x4 acc[4][4])
{
  const int lane = t & 63, w = t >> 6;
  const int wr = (w >> 1) << 6, wc = (w & 1) << 6;
  const int iA = (lane >> 4)*128 + wr + (lane & 15);
  const int iB = (lane >> 4)*128 + wc + (lane & 15);
#define STAGEK(bi, k0) do { \
    char* _b = lds + (bi)*16384; \
    gload16(pA0 + (k0),      _b + t*16); \
    gload16(pA0 + (k0) + 16, _b + (256+t)*16); \
    gload16(pB0 + (k0),      _b + 8192 + t*16); \
    gload16(pB0 + (k0) + 16, _b + 8192 + (256+t)*16); \
  } while(0)
  STAGEK(0, 0);
  __syncthreads();
  int cur = 0;
  for (int k0 = 0; k0 < K; k0 += 32) {
    if (k0 + 32 < K) STAGEK(cur^1, k0 + 32);
    const bf16x8* fA = (const bf16x8*)(lds + cur*16384);
    const bf16x8* fB = (const bf16x8*)(lds + cur*16384 + 8192);
    bf16x8 a[4], b[4];
    #pragma unroll
    for (int m = 0; m < 4; ++m) a[m] = fA[iA + m*16];
    #pragma unroll
    for (int n = 0; n < 4; ++n) b[n] = fB[iB + n*16];
    #pragma unroll
    for (int m = 0; m < 4; ++m)
      #pragma unroll
      for (int n = 0; n < 4; ++n)
        acc[m][n] = __builtin_amdgcn_mfma_f32_16x16x32_bf16(a[m], b[n], acc[m][n], 0, 0, 0);
    __syncthreads();
    cur ^= 1;
  }
#undef STAGEK
}

// ---------------- dense GEMM with optional split-K ----------------
// mode 0: outb = f2b(acc + bias[col]); mode 2: atomicAdd(outf, acc)
__global__ __launch_bounds__(256) void gemm_proj(
    const unsigned short* __restrict__ A, const unsigned short* __restrict__ Bt,
    const float* __restrict__ bias, float* __restrict__ outf,
    unsigned short* __restrict__ outb, int M, int Nn, int K, int KS, int mode)
{
  __shared__ __align__(16) char lds[32768];
  const int t = threadIdx.x;
  const int nblk = Nn >> 7;
  const int chunk = blockIdx.x / nblk;
  const int n0 = (blockIdx.x - chunk*nblk) << 7;
  const int m0 = blockIdx.y << 7;
  const int Kc = K / KS;
  const int kbase = chunk * Kc;
  const int ridx = t & 127, kc = t >> 7;
  const unsigned short* pA0 = A + (size_t)(m0 + ridx)*K + kbase + kc*8;
  const unsigned short* pB0 = Bt + (size_t)(n0 + ridx)*K + kbase + kc*8;
  f32x4 acc[4][4] = {};
  mfma_kloop(pA0, pB0, lds, t, Kc, acc);
  const int lane = t & 63, w = t >> 6;
  const int wr = (w>>1)<<6, wc = (w&1)<<6, lq = lane>>4, lr = lane&15;
  #pragma unroll
  for (int m = 0; m < 4; ++m)
    #pragma unroll
    for (int r = 0; r < 4; ++r) {
      int row = m0 + wr + m*16 + lq*4 + r;
      #pragma unroll
      for (int n = 0; n < 4; ++n) {
        int col = n0 + wc + n*16 + lr;
        if (mode == 0) outb[(size_t)row*Nn + col] = f2b(acc[m][n][r] + bias[col]);
        else atomicAdd(&outf[(size_t)row*Nn + col], acc[m][n][r]);
      }
    }
}

// ---------------- grouped MoE GEMM1 (row-block table) ----------------
__global__ __launch_bounds__(256) void moe_gemm1(
    const unsigned short* __restrict__ x1b, const unsigned short* __restrict__ W1t,
    const float* __restrict__ b1, const int* __restrict__ counts,
    const int* __restrict__ offs, const int* __restrict__ toklist,
    const int2* __restrict__ rbmap, unsigned short* __restrict__ hb)
{
  const int2 rbe = rbmap[blockIdx.y];
  if (rbe.x < 0) return;
  const int e = rbe.x, r0 = rbe.y, cnt = counts[e];
  __shared__ __align__(16) char lds[32768];
  const int t = threadIdx.x, n0 = blockIdx.x*128;
  const int ridx = t & 127, kc = t >> 7;
  const int rg = r0 + ridx;
  const int tok = toklist[e*Nz + (rg < cnt ? rg : 0)];
  const unsigned short* pA0 = x1b + (size_t)tok*Dz + kc*8;
  const unsigned short* pB0 = W1t + ((size_t)e*FFz + n0 + ridx)*Dz + kc*8;
  f32x4 acc[4][4] = {};
  mfma_kloop(pA0, pB0, lds, t, Dz, acc);
  const int lane = t & 63, w = t >> 6;
  const int wr = (w>>1)<<6, wc = (w&1)<<6, lq = lane>>4, lr = lane&15;
  const int base = offs[e] + r0;
  #pragma unroll
  for (int m = 0; m < 4; ++m)
    #pragma unroll
    for (int r = 0; r < 4; ++r) {
      int row = wr + m*16 + lq*4 + r;
      if (r0 + row >= cnt) continue;
      #pragma unroll
      for (int n = 0; n < 4; ++n) {
        int col = n0 + wc + n*16 + lr;
        hb[(size_t)(base+row)*FFz + col] = f2b(gelu_f(acc[m][n][r] + b1[e*FFz + col]));
      }
    }
}

// ---------------- grouped MoE GEMM2, split-K x4, atomic fp32 ----------------
__global__ __launch_bounds__(256) void moe_gemm2(
    const unsigned short* __restrict__ hb, const unsigned short* __restrict__ W2t,
    const int* __restrict__ counts, const int* __restrict__ offs,
    const int2* __restrict__ rbmap, float* __restrict__ y)
{
  const int2 rbe = rbmap[blockIdx.y];
  if (rbe.x < 0) return;
  const int e = rbe.x, r0 = rbe.y, cnt = counts[e];
  __shared__ __align__(16) char lds[32768];
  const int t = threadIdx.x;
  const int chunk = blockIdx.x >> 3;
  const int n0 = (blockIdx.x & 7) << 7;
  const int kbase = chunk * (FFz/4);
  const int ridx = t & 127, kc = t >> 7;
  const int rg = r0 + ridx;
  const int slot = offs[e] + (rg < cnt ? rg : 0);
  const unsigned short* pA0 = hb + (size_t)slot*FFz + kbase + kc*8;
  const unsigned short* pB0 = W2t + ((size_t)e*Dz + n0 + ridx)*FFz + kbase + kc*8;
  f32x4 acc[4][4] = {};
  mfma_kloop(pA0, pB0, lds, t, FFz/4, acc);
  const int lane = t & 63, w = t >> 6;
  const int wr = (w>>1)<<6, wc = (w&1)<<6, lq = lane>>4, lr = lane&15;
  const int base = offs[e] + r0;
  #pragma unroll
  for (int m = 0; m < 4; ++m)
    #pragma unroll
    for (int r = 0; r < 4; ++r) {
      int row = wr + m*16 + lq*4 + r;
      if (r0 + row >= cnt) continue;
      #pragma unroll
      for (int n = 0; n < 4; ++n) {
        int col = n0 + wc + n*16 + lr;
        atomicAdd(&y[(size_t)(base+row)*Dz + col], acc[m][n][r]);
      }
    }
}

// ---------------- RoPE (in-place on fused qkv buffer) ----------------
__global__ void rope_qk(unsigned short* __restrict__ qkv){
  int gid = blockIdx.x*blockDim.x + threadIdx.x;
  int i = gid & 31;
  int h = (gid >> 5) & (Hz-1);
  int n = gid >> 9;
  int s = n & (Sz-1);
  float inv = powf(10000.0f, -(float)(2*i)/64.0f);
  float ang = (float)s * inv;
  float cs = cosf(ang), sn = sinf(ang);
  size_t base = (size_t)n*QKVSz + h*HDz + i;
  float q1 = b2f(qkv[base]), q2 = b2f(qkv[base+32]);
  qkv[base]    = f2b(q1*cs - q2*sn);
  qkv[base+32] = f2b(q2*cs + q1*sn);
  float k1 = b2f(qkv[base+Dz]), k2 = b2f(qkv[base+Dz+32]);
  qkv[base+Dz]    = f2b(k1*cs - k2*sn);
  qkv[base+Dz+32] = f2b(k2*cs + k1*sn);
}

// ---------------- MFMA flash attention (q/k/v strided QKVSz) ----------------
__global__ __launch_bounds__(256) void attn_mfma(
    const unsigned short* __restrict__ q, const unsigned short* __restrict__ k,
    const unsigned short* __restrict__ v, unsigned short* __restrict__ ao)
{
  __shared__ __align__(16) char lds[24576];
  char* Klds = lds;
  char* Vlds = lds + 8192;
  char* Plds = lds + 16384;

  const int t = threadIdx.x;
  const int lane = t & 63, w = t >> 6;
  const int p15 = lane & 15, g = lane >> 4;
  const int bh = blockIdx.x >> 4;
  const int qblk = blockIdx.x & 15;
  const int b = bh >> 4, h = bh & 15;
  const size_t hoff = (size_t)h*HDz;
  const int q0 = qblk*64 + w*16;

  const size_t qrow = (size_t)(b*Sz + q0 + p15)*QKVSz + hoff;
  const bf16x8 qf0 = *(const bf16x8*)(q + qrow + 8*g);
  const bf16x8 qf1 = *(const bf16x8*)(q + qrow + 32 + 8*g);

  char* Pw = Plds + w*2048;

  float mrun = -INFINITY, lsum = 0.f;
  f32x4 acc_o[4] = {};

  const unsigned short* kbh = k + (size_t)(b*Sz)*QKVSz + hoff;
  const unsigned short* vbh = v + (size_t)(b*Sz)*QKVSz + hoff;

  for (int t0 = 0; t0 < Sz; t0 += 64) {
    __syncthreads();
    #pragma unroll
    for (int u = 0; u < 2; ++u) {
      int j = t + 256*u;
      int kkv = j >> 3, kdc = (j & 7) ^ (kkv & 7);
      gload16(kbh + (size_t)(t0 + kkv)*QKVSz + 8*kdc, Klds + j*16);
      int va = j >> 5, vbb = (j >> 3) & 3, vr = (j >> 1) & 3, vc = 8*(j & 1);
      gload16(vbh + (size_t)(t0 + 4*va + vr)*QKVSz + 16*vbb + vc, Vlds + j*16);
    }
    __syncthreads();

    f32x4 sc[4];
    #pragma unroll
    for (int mt = 0; mt < 4; ++mt) {
      int kv = mt*16 + p15;
      bf16x8 a0 = *(const bf16x8*)(Klds + kv*128 + ((g     ^ (kv & 7))*16));
      bf16x8 a1 = *(const bf16x8*)(Klds + kv*128 + (((g+4) ^ (kv & 7))*16));
      f32x4 z = {};
      z = __builtin_amdgcn_mfma_f32_16x16x32_bf16(a0, qf0, z, 0, 0, 0);
      z = __builtin_amdgcn_mfma_f32_16x16x32_bf16(a1, qf1, z, 0, 0, 0);
      sc[mt] = z;
    }

    float pmax = -INFINITY;
    #pragma unroll
    for (int mt = 0; mt < 4; ++mt)
      #pragma unroll
      for (int r = 0; r < 4; ++r) {
        sc[mt][r] *= 0.125f;
        pmax = fmaxf(pmax, sc[mt][r]);
      }
    pmax = fmaxf(pmax, __shfl_xor(pmax, 16));
    pmax = fmaxf(pmax, __shfl_xor(pmax, 32));
    float mnew = fmaxf(mrun, pmax);
    float resc = __expf(mrun - mnew);
    mrun = mnew;
    float ps = 0.f;
    #pragma unroll
    for (int mt = 0; mt < 4; ++mt) {
      float p0 = __expf(sc[mt][0] - mnew);
      float p1 = __expf(sc[mt][1] - mnew);
      float p2 = __expf(sc[mt][2] - mnew);
      float p3 = __expf(sc[mt][3] - mnew);
      ps += (p0 + p1) + (p2 + p3);
      ushort4 pk;
      pk.x = f2b(p0); pk.y = f2b(p1); pk.z = f2b(p2); pk.w = f2b(p3);
      *(ushort4*)(Pw + ((p15*128 + mt*32 + g*8) ^ ((p15 & 7) << 4))) = pk;
    }
    ps += __shfl_xor(ps, 16);
    ps += __shfl_xor(ps, 32);
    lsum = lsum*resc + ps;
    #pragma unroll
    for (int bb = 0; bb < 4; ++bb) {
      acc_o[bb][0] *= resc; acc_o[bb][1] *= resc;
      acc_o[bb][2] *= resc; acc_o[bb][3] *= resc;
    }

    #pragma unroll
    for (int bb = 0; bb < 4; ++bb) {
      #pragma unroll
      for (int kh = 0; kh < 2; ++kh) {
        const __attribute__((address_space(3))) char* vp =
          (const __attribute__((address_space(3))) char*)
            (Vlds + 4096*kh + 1024*g + 128*bb + 8*p15);
        bf16x4 v0, v1;
        asm volatile("ds_read_b64_tr_b16 %0, %2\n\t"
                     "ds_read_b64_tr_b16 %1, %2 offset:512\n\t"
                     "s_waitcnt lgkmcnt(0)"
                     : "=v"(v0), "=v"(v1) : "v"(vp) : "memory");
        __builtin_amdgcn_sched_barrier(0);
        union { bf16x4 hh[2]; bf16x8 full; } af;
        af.hh[0] = v0; af.hh[1] = v1;
        bf16x8 pf = *(const bf16x8*)(Pw + ((p15*128 + kh*64 + g*16) ^ ((p15 & 7) << 4)));
        acc_o[bb] = __builtin_amdgcn_mfma_f32_16x16x32_bf16(af.full, pf, acc_o[bb], 0, 0, 0);
      }
    }
  }

  const float inv = 1.0f / lsum;
  const size_t orow = (size_t)(b*Sz + q0 + p15)*Dz + hoff;
  #pragma unroll
  for (int bb = 0; bb < 4; ++bb) {
    ushort4 o;
    o.x = f2b(acc_o[bb][0]*inv);
    o.y = f2b(acc_o[bb][1]*inv);
    o.z = f2b(acc_o[bb][2]*inv);
    o.w = f2b(acc_o[bb][3]*inv);
    *(ushort4*)(ao + orow + 16*bb + 4*g) = o;
  }
}

// ---------------- LayerNorm 1 ----------------
__global__ __launch_bounds__(256) void ln1_k(
    const float* __restrict__ a, const float* __restrict__ g,
    const float* __restrict__ beta, float* __restrict__ outf,
    unsigned short* __restrict__ outb)
{
  int n = blockIdx.x, t = threadIdx.x;
  __shared__ float red[256];
  float vals[4]; float s = 0.f;
  #pragma unroll
  for (int i = 0; i < 4; ++i) {
    int d = t + i*256;
    float x = a[(size_t)n*Dz + d];
    vals[i] = x; s += x;
  }
  red[t] = s; __syncthreads();
  for (int st = 128; st; st >>= 1) { if (t < st) red[t] += red[t+st]; __syncthreads(); }
  float mean = red[0] * (1.0f/Dz);
  __syncthreads();
  float vsum = 0.f;
  #pragma unroll
  for (int i = 0; i < 4; ++i){ float dd = vals[i]-mean; vsum += dd*dd; }
  red[t] = vsum; __syncthreads();
  for (int st = 128; st; st >>= 1) { if (t < st) red[t] += red[t+st]; __syncthreads(); }
  float rs = rsqrtf(red[0]*(1.0f/Dz) + EPSz);
  #pragma unroll
  for (int i = 0; i < 4; ++i) {
    int d = t + i*256;
    float o = (vals[i]-mean)*rs*g[d] + beta[d];
    outf[(size_t)n*Dz + d] = o;
    outb[(size_t)n*Dz + d] = f2b(o);
  }
}

// ---------------- gate ----------------
__global__ __launch_bounds__(64) void gate_topk(
    const float* __restrict__ x1, const float* __restrict__ Wg,
    const float* __restrict__ bg, int* __restrict__ counts,
    int* __restrict__ toklist, int4* __restrict__ tokinfo,
    float2* __restrict__ tokw)
{
  int n = blockIdx.x, lane = threadIdx.x;
  const float* row = x1 + (size_t)n*Dz;
  float acc[8] = {0,0,0,0,0,0,0,0};
  for (int d = lane; d < Dz; d += 64) {
    float xv = row[d];
    const float4* wp = (const float4*)(Wg + (size_t)d*Ez);
    float4 w0 = wp[0], w1 = wp[1];
    acc[0] += xv*w0.x; acc[1] += xv*w0.y; acc[2] += xv*w0.z; acc[3] += xv*w0.w;
    acc[4] += xv*w1.x; acc[5] += xv*w1.y; acc[6] += xv*w1.z; acc[7] += xv*w1.w;
  }
  #pragma unroll
  for (int e = 0; e < 8; ++e)
    #pragma unroll
    for (int off = 32; off; off >>= 1) acc[e] += __shfl_xor(acc[e], off);
  if (lane == 0) {
    float lg[8]; float mx = -INFINITY;
    #pragma unroll
    for (int e = 0; e < 8; ++e){ lg[e] = acc[e] + bg[e]; mx = fmaxf(mx, lg[e]); }
    float p[8];
    #pragma unroll
    for (int e = 0; e < 8; ++e) p[e] = __expf(lg[e]-mx);
    int e1 = 0; float m1 = p[0];
    for (int e = 1; e < 8; ++e) if (p[e] > m1){ m1 = p[e]; e1 = e; }
    int e2 = -1; float m2 = -INFINITY;
    for (int e = 0; e < 8; ++e) if (e != e1 && p[e] > m2){ m2 = p[e]; e2 = e; }
    float inv = 1.0f/(m1+m2);
    int p1 = atomicAdd(&counts[e1], 1); toklist[e1*Nz + p1] = n;
    int p2 = atomicAdd(&counts[e2], 1); toklist[e2*Nz + p2] = n;
    tokinfo[n] = make_int4(e1, p1, e2, p2);
    tokw[n] = make_float2(m1*inv, m2*inv);
  }
}

// ---------------- prefix + row-block table ----------------
__global__ void prefix_k(const int* __restrict__ counts, int* __restrict__ offs,
                         int2* __restrict__ rbmap){
  if (threadIdx.x == 0 && blockIdx.x == 0) {
    int s = 0;
    for (int e = 0; e < Ez; ++e){ offs[e] = s; s += counts[e]; }
    offs[Ez] = s;
    int rb = 0;
    for (int e = 0; e < Ez; ++e) {
      int nrb = (counts[e] + 127) >> 7;
      for (int i = 0; i < nrb; ++i) rbmap[rb++] = make_int2(e, i*128);
    }
    for (; rb < NRB; ++rb) rbmap[rb] = make_int2(-1, 0);
  }
}

// ---------------- final combine + LayerNorm (b2 folded here) ----------------
__global__ __launch_bounds__(256) void ln2_k(
    const float* __restrict__ x1, const float* __restrict__ y,
    const float* __restrict__ b2, const int4* __restrict__ tokinfo,
    const float2* __restrict__ tokw, const int* __restrict__ offs,
    const float* __restrict__ g, const float* __restrict__ beta,
    float* __restrict__ out)
{
  int n = blockIdx.x, t = threadIdx.x;
  __shared__ float red[256];
  int4 ti = tokinfo[n]; float2 tw = tokw[n];
  const float* y1 = y + (size_t)(offs[ti.x] + ti.y)*Dz;
  const float* y2 = y + (size_t)(offs[ti.z] + ti.w)*Dz;
  const float* b2a = b2 + (size_t)ti.x*Dz;
  const float* b2b = b2 + (size_t)ti.z*Dz;
  float vals[4]; float s = 0.f;
  #pragma unroll
  for (int i = 0; i < 4; ++i) {
    int d = t + i*256;
    float x = x1[(size_t)n*Dz + d] + tw.x*(y1[d] + b2a[d]) + tw.y*(y2[d] + b2b[d]);
    vals[i] = x; s += x;
  }
  red[t] = s; __syncthreads();
  for (int st = 128; st; st >>= 1) { if (t < st) red[t] += red[t+st]; __syncthreads(); }
  float mean = red[0] * (1.0f/Dz);
  __syncthreads();
  float vsum = 0.f;
  #pragma unroll
  for (int i = 0; i < 4; ++i){ float dd = vals[i]-mean; vsum += dd*dd; }
  red[t] = vsum; __syncthreads();
  for (int st = 128; st; st >>= 1) { if (t < st) red[t] += red[t+st]; __syncthreads(); }
  float rs = rsqrtf(red[0]*(1.0f/Dz) + EPSz);
  #pragma unroll
  for (int i = 0; i < 4; ++i) {
    int d = t + i*256;
    out[(size_t)n*Dz + d] = (vals[i]-mean)*rs*g[d] + beta[d];
  }
}

extern "C" void kernel_launch(void* const* d_in, const int* in_sizes, int n_in,
                              void* d_out, int out_size, void* d_ws, size_t ws_size,
                              hipStream_t stream)
{
  const float* x  = (const float*)d_in[0];
  const float* Wq = (const float*)d_in[1];
  const float* bq = (const float*)d_in[2];
  const float* Wk = (const float*)d_in[3];
  const float* bk = (const float*)d_in[4];
  const float* Wv = (const float*)d_in[5];
  const float* bv = (const float*)d_in[6];
  const float* Wo = (const float*)d_in[7];
  const float* bo = (const float*)d_in[8];
  const float* Wg = (const float*)d_in[9];
  const float* bg = (const float*)d_in[10];
  const float* W1 = (const float*)d_in[11];
  const float* b1 = (const float*)d_in[12];
  const float* W2 = (const float*)d_in[13];
  const float* b2 = (const float*)d_in[14];
  const float* g1 = (const float*)d_in[15];
  const float* be1= (const float*)d_in[16];
  const float* g2 = (const float*)d_in[17];
  const float* be2= (const float*)d_in[18];
  float* out = (float*)d_out;

  const size_t PD = (size_t)Dz*Dz;
  const size_t ND = (size_t)Nz*Dz;
  unsigned short* Wqt = (unsigned short*)d_ws;   // [3072][1024] fused B
  unsigned short* Wkt = Wqt + PD;
  unsigned short* Wvt = Wkt + PD;
  unsigned short* Wot = Wvt + PD;
  unsigned short* W1t = Wot + PD;
  unsigned short* W2t = W1t + (size_t)Ez*FFz*Dz;
  unsigned short* hb  = W2t + (size_t)Ez*FFz*Dz;
  unsigned short* xb  = hb  + (size_t)2*Nz*FFz;
  unsigned short* qkvb= xb  + ND;                 // [Nz][3072]
  unsigned short* aob = qkvb + (size_t)Nz*QKVSz;
  unsigned short* x1b = aob + ND;
  float* x1 = (float*)(x1b + ND);
  float* t1 = x1 + ND;
  float* y  = t1 + ND;                            // [2*Nz][Dz]
  float* bqkv = y + (size_t)2*Nz*Dz;
  int4*  tokinfo = (int4*)(bqkv + QKVSz);
  float2* tokw   = (float2*)(tokinfo + Nz);
  int* counts  = (int*)(tokw + Nz);
  int* offs    = counts + Ez;
  int* toklist = offs + Ez + 1;
  int2* rbmap  = (int2*)(toklist + Ez*Nz);

  dim3 blk(256);
  transpose_cvt<<<dim3(16,16,1), blk, 0, stream>>>(Wq, Wqt, Dz, Dz);
  transpose_cvt<<<dim3(16,16,1), blk, 0, stream>>>(Wk, Wkt, Dz, Dz);
  transpose_cvt<<<dim3(16,16,1), blk, 0, stream>>>(Wv, Wvt, Dz, Dz);
  transpose_cvt<<<dim3(16,16,1), blk, 0, stream>>>(Wo, Wot, Dz, Dz);
  transpose_cvt<<<dim3(FFz/64, Dz/64, Ez), blk, 0, stream>>>(W1, W1t, Dz, FFz);
  transpose_cvt<<<dim3(Dz/64, FFz/64, Ez), blk, 0, stream>>>(W2, W2t, FFz, Dz);
  concat3<<<12, blk, 0, stream>>>(bq, bk, bv, bqkv);
  cvt_bf16<<<(int)(ND/4/256), blk, 0, stream>>>(x, xb, (int)ND);

  // fused QKV: [2048,1024] @ [1024,3072] -> qkvb
  gemm_proj<<<dim3(QKVSz/128, Nz/128), blk, 0, stream>>>(
      xb, Wqt, bqkv, nullptr, qkvb, Nz, QKVSz, Dz, 1, 0);
  rope_qk<<<(Nz*Hz*32)/256, blk, 0, stream>>>(qkvb);
  attn_mfma<<<dim3(Bz*Hz*(Sz/64)), blk, 0, stream>>>(qkvb, qkvb + Dz, qkvb + 2*Dz, aob);

  // O projection: t1 = x + bo, then split-K x2 atomic accumulate
  init_t1<<<(int)(ND/4/256), blk, 0, stream>>>(x, bo, t1);
  gemm_proj<<<dim3((Dz/128)*2, Nz/128), blk, 0, stream>>>(
      aob, Wot, nullptr, t1, nullptr, Nz, Dz, Dz, 2, 2);
  ln1_k<<<Nz, blk, 0, stream>>>(t1, g1, be1, x1, x1b);

  hipMemsetAsync(counts, 0, Ez*sizeof(int), stream);
  hipMemsetAsync(y, 0, (size_t)2*Nz*Dz*sizeof(float), stream);
  gate_topk<<<Nz, dim3(64), 0, stream>>>(x1, Wg, bg, counts, toklist, tokinfo, tokw);
  prefix_k<<<1, dim3(64), 0, stream>>>(counts, offs, rbmap);
  moe_gemm1<<<dim3(FFz/128, NRB), blk, 0, stream>>>(x1b, W1t, b1, counts, offs, toklist, rbmap, hb);
  moe_gemm2<<<dim3((Dz/128)*4, NRB), blk, 0, stream>>>(hb, W2t, counts, offs, rbmap, y);
  ln2_k<<<Nz, blk, 0, stream>>>(x1, y, b2, tokinfo, tokw, offs, g2, be2, out);
}

// Round 7
// 493.982 us; speedup vs baseline: 6.8384x; 1.0511x over previous
//
#include <hip/hip_runtime.h>
#include <cmath>

#define Bz 2
#define Sz 1024
#define Dz 1024
#define Hz 16
#define HDz 64
#define Ez 8
#define FFz 4096
#define Nz (Bz*Sz)
#define SLOTSz (2*Nz)
#define QKVSz (3*Dz)
#define EPSz 1e-5f
#define NRB 48

typedef __attribute__((ext_vector_type(8))) short bf16x8;
typedef __attribute__((ext_vector_type(4))) short bf16x4;
typedef __attribute__((ext_vector_type(4))) float f32x4;
typedef __attribute__((ext_vector_type(8))) unsigned short ushortx8;

__device__ __forceinline__ float b2f(unsigned short u){
  union { unsigned int i; float f; } x; x.i = ((unsigned int)u) << 16; return x.f;
}
__device__ __forceinline__ unsigned short f2b(float f){
  union { float f; unsigned int i; } x; x.f = f;
  unsigned int r = x.i + 0x7FFFu + ((x.i >> 16) & 1u);
  return (unsigned short)(r >> 16);
}
__device__ __forceinline__ float gelu_f(float x){
  return 0.5f*x*(1.0f + erff(x*0.70710678118654752f));
}
__device__ __forceinline__ void gload16(const void* g, void* l){
  __builtin_amdgcn_global_load_lds(
    (const __attribute__((address_space(1))) unsigned int*)g,
    (__attribute__((address_space(3))) unsigned int*)l, 16, 0, 0);
}

// ---------------- fp32 -> bf16 plain convert ----------------
__global__ __launch_bounds__(256) void cvt_bf16(
    const float* __restrict__ in, unsigned short* __restrict__ out, int n)
{
  int i = (blockIdx.x*blockDim.x + threadIdx.x)*4;
  if (i >= n) return;
  float4 v = *(const float4*)(in + i);
  ushort4 o;
  o.x = f2b(v.x); o.y = f2b(v.y); o.z = f2b(v.z); o.w = f2b(v.w);
  *(ushort4*)(out + i) = o;
}

// ---------------- fp32 [z][R][C] -> bf16 [z][C][R], 64x64 tiles ----------------
__global__ __launch_bounds__(256) void transpose_cvt(
    const float* __restrict__ in, unsigned short* __restrict__ out, int R, int C)
{
  __shared__ float tile[64][65];
  const size_t boff = (size_t)blockIdx.z * R * C;
  int c0 = blockIdx.x*64, r0 = blockIdx.y*64;
  int tx = threadIdx.x & 15, ty = threadIdx.x >> 4;   // 16x16
  #pragma unroll
  for (int i = 0; i < 4; ++i) {
    float4 v = *(const float4*)(in + boff + (size_t)(r0+ty+16*i)*C + c0 + tx*4);
    tile[ty+16*i][tx*4+0] = v.x; tile[ty+16*i][tx*4+1] = v.y;
    tile[ty+16*i][tx*4+2] = v.z; tile[ty+16*i][tx*4+3] = v.w;
  }
  __syncthreads();
  int oc = threadIdx.x >> 3;
  int og = threadIdx.x & 7;
  #pragma unroll
  for (int p = 0; p < 2; ++p) {
    int c = oc + p*32;
    ushortx8 u;
    #pragma unroll
    for (int j = 0; j < 8; ++j) u[j] = f2b(tile[og*8+j][c]);
    *(ushortx8*)(out + boff + (size_t)(c0+c)*R + r0 + og*8) = u;
  }
}

// ---------------- bias concat (bq|bk|bv) ----------------
__global__ void concat3(const float* __restrict__ a, const float* __restrict__ b,
                        const float* __restrict__ c, float* __restrict__ o)
{
  int i = blockIdx.x*256 + threadIdx.x;
  if (i >= 3072) return;
  o[i] = (i < 1024) ? a[i] : (i < 2048 ? b[i-1024] : c[i-2048]);
}

// ------- MFMA 128x128xK core: 3-buffer pipeline, counted vmcnt --------
// Loads for tiles t+1, t+2 stay in flight across the barrier. waitcnt+barrier
// fused in one asm so nothing can separate or cross them; sched_barrier fences.
__device__ __forceinline__ void mfma_kloop(
    const unsigned short* __restrict__ pA0,
    const unsigned short* __restrict__ pB0,
    char* lds, int t, int K, f32x4 acc[4][4])
{
  const int lane = t & 63, w = t >> 6;
  const int wr = (w >> 1) << 6, wc = (w & 1) << 6;
  const int iA = (lane >> 4)*128 + wr + (lane & 15);
  const int iB = (lane >> 4)*128 + wc + (lane & 15);
#define STAGEK(bi, k0) do { \
    char* _b = lds + (bi)*16384; \
    gload16(pA0 + (k0),      _b + t*16); \
    gload16(pA0 + (k0) + 16, _b + (256+t)*16); \
    gload16(pB0 + (k0),      _b + 8192 + t*16); \
    gload16(pB0 + (k0) + 16, _b + 8192 + (256+t)*16); \
  } while(0)
#define WAITBAR4 do { __builtin_amdgcn_sched_barrier(0); \
    asm volatile("s_waitcnt vmcnt(4) lgkmcnt(0)\n\ts_barrier" ::: "memory"); \
    __builtin_amdgcn_sched_barrier(0); } while(0)
#define WAITBAR0 do { __builtin_amdgcn_sched_barrier(0); \
    asm volatile("s_waitcnt vmcnt(0) lgkmcnt(0)\n\ts_barrier" ::: "memory"); \
    __builtin_amdgcn_sched_barrier(0); } while(0)
  const int nt = K >> 5;
  STAGEK(0, 0);
  if (nt > 1) { STAGEK(1, 32); WAITBAR4; }
  else        {                WAITBAR0; }
  int cur = 0;
  for (int ti = 0; ti < nt; ++ti) {
    const bool more = (ti + 2 < nt);
    if (more) {
      int stg = cur + 2; if (stg >= 3) stg -= 3;
      STAGEK(stg, (ti + 2) << 5);
    }
    const bf16x8* fA = (const bf16x8*)(lds + cur*16384);
    const bf16x8* fB = (const bf16x8*)(lds + cur*16384 + 8192);
    bf16x8 a[4], b[4];
    #pragma unroll
    for (int m = 0; m < 4; ++m) a[m] = fA[iA + m*16];
    #pragma unroll
    for (int n = 0; n < 4; ++n) b[n] = fB[iB + n*16];
    #pragma unroll
    for (int m = 0; m < 4; ++m)
      #pragma unroll
      for (int n = 0; n < 4; ++n)
        acc[m][n] = __builtin_amdgcn_mfma_f32_16x16x32_bf16(a[m], b[n], acc[m][n], 0, 0, 0);
    if (more) WAITBAR4; else WAITBAR0;
    cur += 1; if (cur >= 3) cur -= 3;
  }
#undef STAGEK
#undef WAITBAR4
#undef WAITBAR0
}

// ---------------- dense GEMM with optional split-K (deterministic) ----------------
// mode 0: outb = f2b(acc + bias[col]); mode 1: outf[chunk][row][col] = acc (plain store)
__global__ __launch_bounds__(256) void gemm_proj(
    const unsigned short* __restrict__ A, const unsigned short* __restrict__ Bt,
    const float* __restrict__ bias, float* __restrict__ outf,
    unsigned short* __restrict__ outb, int M, int Nn, int K, int KS, int mode)
{
  __shared__ __align__(16) char lds[49152];
  const int t = threadIdx.x;
  const int nblk = Nn >> 7;
  const int chunk = blockIdx.x / nblk;
  const int n0 = (blockIdx.x - chunk*nblk) << 7;
  const int m0 = blockIdx.y << 7;
  const int Kc = K / KS;
  const int kbase = chunk * Kc;
  const int ridx = t & 127, kc = t >> 7;
  const unsigned short* pA0 = A + (size_t)(m0 + ridx)*K + kbase + kc*8;
  const unsigned short* pB0 = Bt + (size_t)(n0 + ridx)*K + kbase + kc*8;
  f32x4 acc[4][4] = {};
  mfma_kloop(pA0, pB0, lds, t, Kc, acc);
  const int lane = t & 63, w = t >> 6;
  const int wr = (w>>1)<<6, wc = (w&1)<<6, lq = lane>>4, lr = lane&15;
  #pragma unroll
  for (int m = 0; m < 4; ++m)
    #pragma unroll
    for (int r = 0; r < 4; ++r) {
      int row = m0 + wr + m*16 + lq*4 + r;
      #pragma unroll
      for (int n = 0; n < 4; ++n) {
        int col = n0 + wc + n*16 + lr;
        if (mode == 0) outb[(size_t)row*Nn + col] = f2b(acc[m][n][r] + bias[col]);
        else outf[((size_t)chunk*M + row)*Nn + col] = acc[m][n][r];
      }
    }
}

// ---------------- grouped MoE GEMM1 (row-block table) ----------------
__global__ __launch_bounds__(256) void moe_gemm1(
    const unsigned short* __restrict__ x1b, const unsigned short* __restrict__ W1t,
    const float* __restrict__ b1, const int* __restrict__ counts,
    const int* __restrict__ offs, const int* __restrict__ toklist,
    const int2* __restrict__ rbmap, unsigned short* __restrict__ hb)
{
  const int2 rbe = rbmap[blockIdx.y];
  if (rbe.x < 0) return;
  const int e = rbe.x, r0 = rbe.y, cnt = counts[e];
  __shared__ __align__(16) char lds[49152];
  const int t = threadIdx.x, n0 = blockIdx.x*128;
  const int ridx = t & 127, kc = t >> 7;
  const int rg = r0 + ridx;
  const int tok = toklist[e*Nz + (rg < cnt ? rg : 0)];
  const unsigned short* pA0 = x1b + (size_t)tok*Dz + kc*8;
  const unsigned short* pB0 = W1t + ((size_t)e*FFz + n0 + ridx)*Dz + kc*8;
  f32x4 acc[4][4] = {};
  mfma_kloop(pA0, pB0, lds, t, Dz, acc);
  const int lane = t & 63, w = t >> 6;
  const int wr = (w>>1)<<6, wc = (w&1)<<6, lq = lane>>4, lr = lane&15;
  const int base = offs[e] + r0;
  #pragma unroll
  for (int m = 0; m < 4; ++m)
    #pragma unroll
    for (int r = 0; r < 4; ++r) {
      int row = wr + m*16 + lq*4 + r;
      if (r0 + row >= cnt) continue;
      #pragma unroll
      for (int n = 0; n < 4; ++n) {
        int col = n0 + wc + n*16 + lr;
        hb[(size_t)(base+row)*FFz + col] = f2b(gelu_f(acc[m][n][r] + b1[e*FFz + col]));
      }
    }
}

// ------- grouped MoE GEMM2, split-K x2 -> per-chunk partial stores (deterministic) ----
__global__ __launch_bounds__(256) void moe_gemm2(
    const unsigned short* __restrict__ hb, const unsigned short* __restrict__ W2t,
    const int* __restrict__ counts, const int* __restrict__ offs,
    const int2* __restrict__ rbmap, float* __restrict__ yp)
{
  const int2 rbe = rbmap[blockIdx.y];
  if (rbe.x < 0) return;
  const int e = rbe.x, r0 = rbe.y, cnt = counts[e];
  __shared__ __align__(16) char lds[49152];
  const int t = threadIdx.x;
  const int chunk = blockIdx.x >> 3;
  const int n0 = (blockIdx.x & 7) << 7;
  const int kbase = chunk * (FFz/2);
  const int ridx = t & 127, kc = t >> 7;
  const int rg = r0 + ridx;
  const int slot = offs[e] + (rg < cnt ? rg : 0);
  const unsigned short* pA0 = hb + (size_t)slot*FFz + kbase + kc*8;
  const unsigned short* pB0 = W2t + ((size_t)e*Dz + n0 + ridx)*FFz + kbase + kc*8;
  f32x4 acc[4][4] = {};
  mfma_kloop(pA0, pB0, lds, t, FFz/2, acc);
  const int lane = t & 63, w = t >> 6;
  const int wr = (w>>1)<<6, wc = (w&1)<<6, lq = lane>>4, lr = lane&15;
  const int base = offs[e] + r0;
  #pragma unroll
  for (int m = 0; m < 4; ++m)
    #pragma unroll
    for (int r = 0; r < 4; ++r) {
      int row = wr + m*16 + lq*4 + r;
      if (r0 + row >= cnt) continue;
      #pragma unroll
      for (int n = 0; n < 4; ++n) {
        int col = n0 + wc + n*16 + lr;
        yp[((size_t)chunk*SLOTSz + base + row)*Dz + col] = acc[m][n][r];
      }
    }
}

// ---------------- RoPE (in-place on fused qkv buffer) ----------------
__global__ void rope_qk(unsigned short* __restrict__ qkv){
  int gid = blockIdx.x*blockDim.x + threadIdx.x;
  int i = gid & 31;
  int h = (gid >> 5) & (Hz-1);
  int n = gid >> 9;
  int s = n & (Sz-1);
  float inv = powf(10000.0f, -(float)(2*i)/64.0f);
  float ang = (float)s * inv;
  float cs = cosf(ang), sn = sinf(ang);
  size_t base = (size_t)n*QKVSz + h*HDz + i;
  float q1 = b2f(qkv[base]), q2 = b2f(qkv[base+32]);
  qkv[base]    = f2b(q1*cs - q2*sn);
  qkv[base+32] = f2b(q2*cs + q1*sn);
  float k1 = b2f(qkv[base+Dz]), k2 = b2f(qkv[base+Dz+32]);
  qkv[base+Dz]    = f2b(k1*cs - k2*sn);
  qkv[base+Dz+32] = f2b(k2*cs + k1*sn);
}

// ---------------- MFMA flash attention (round-5 proven version) ----------------
__global__ __launch_bounds__(256) void attn_mfma(
    const unsigned short* __restrict__ q, const unsigned short* __restrict__ k,
    const unsigned short* __restrict__ v, unsigned short* __restrict__ ao)
{
  __shared__ __align__(16) char lds[24576];
  char* Klds = lds;
  char* Vlds = lds + 8192;
  char* Plds = lds + 16384;

  const int t = threadIdx.x;
  const int lane = t & 63, w = t >> 6;
  const int p15 = lane & 15, g = lane >> 4;
  const int bh = blockIdx.x >> 4;
  const int qblk = blockIdx.x & 15;
  const int b = bh >> 4, h = bh & 15;
  const size_t hoff = (size_t)h*HDz;
  const int q0 = qblk*64 + w*16;

  const size_t qrow = (size_t)(b*Sz + q0 + p15)*QKVSz + hoff;
  const bf16x8 qf0 = *(const bf16x8*)(q + qrow + 8*g);
  const bf16x8 qf1 = *(const bf16x8*)(q + qrow + 32 + 8*g);

  char* Pw = Plds + w*2048;

  float mrun = -INFINITY, lsum = 0.f;
  f32x4 acc_o[4] = {};

  const unsigned short* kbh = k + (size_t)(b*Sz)*QKVSz + hoff;
  const unsigned short* vbh = v + (size_t)(b*Sz)*QKVSz + hoff;

  for (int t0 = 0; t0 < Sz; t0 += 64) {
    __syncthreads();
    #pragma unroll
    for (int u = 0; u < 2; ++u) {
      int j = t + 256*u;
      int kkv = j >> 3, kdc = (j & 7) ^ (kkv & 7);
      gload16(kbh + (size_t)(t0 + kkv)*QKVSz + 8*kdc, Klds + j*16);
      int va = j >> 5, vbb = (j >> 3) & 3, vr = (j >> 1) & 3, vc = 8*(j & 1);
      gload16(vbh + (size_t)(t0 + 4*va + vr)*QKVSz + 16*vbb + vc, Vlds + j*16);
    }
    __syncthreads();

    f32x4 sc[4];
    #pragma unroll
    for (int mt = 0; mt < 4; ++mt) {
      int kv = mt*16 + p15;
      bf16x8 a0 = *(const bf16x8*)(Klds + kv*128 + ((g     ^ (kv & 7))*16));
      bf16x8 a1 = *(const bf16x8*)(Klds + kv*128 + (((g+4) ^ (kv & 7))*16));
      f32x4 z = {};
      z = __builtin_amdgcn_mfma_f32_16x16x32_bf16(a0, qf0, z, 0, 0, 0);
      z = __builtin_amdgcn_mfma_f32_16x16x32_bf16(a1, qf1, z, 0, 0, 0);
      sc[mt] = z;
    }

    float pmax = -INFINITY;
    #pragma unroll
    for (int mt = 0; mt < 4; ++mt)
      #pragma unroll
      for (int r = 0; r < 4; ++r) {
        sc[mt][r] *= 0.125f;
        pmax = fmaxf(pmax, sc[mt][r]);
      }
    pmax = fmaxf(pmax, __shfl_xor(pmax, 16));
    pmax = fmaxf(pmax, __shfl_xor(pmax, 32));
    float mnew = fmaxf(mrun, pmax);
    float resc = __expf(mrun - mnew);
    mrun = mnew;
    float ps = 0.f;
    #pragma unroll
    for (int mt = 0; mt < 4; ++mt) {
      float p0 = __expf(sc[mt][0] - mnew);
      float p1 = __expf(sc[mt][1] - mnew);
      float p2 = __expf(sc[mt][2] - mnew);
      float p3 = __expf(sc[mt][3] - mnew);
      ps += (p0 + p1) + (p2 + p3);
      ushort4 pk;
      pk.x = f2b(p0); pk.y = f2b(p1); pk.z = f2b(p2); pk.w = f2b(p3);
      *(ushort4*)(Pw + ((p15*128 + mt*32 + g*8) ^ ((p15 & 7) << 4))) = pk;
    }
    ps += __shfl_xor(ps, 16);
    ps += __shfl_xor(ps, 32);
    lsum = lsum*resc + ps;
    #pragma unroll
    for (int bb = 0; bb < 4; ++bb) {
      acc_o[bb][0] *= resc; acc_o[bb][1] *= resc;
      acc_o[bb][2] *= resc; acc_o[bb][3] *= resc;
    }

    #pragma unroll
    for (int bb = 0; bb < 4; ++bb) {
      #pragma unroll
      for (int kh = 0; kh < 2; ++kh) {
        const __attribute__((address_space(3))) char* vp =
          (const __attribute__((address_space(3))) char*)
            (Vlds + 4096*kh + 1024*g + 128*bb + 8*p15);
        bf16x4 v0, v1;
        asm volatile("ds_read_b64_tr_b16 %0, %2\n\t"
                     "ds_read_b64_tr_b16 %1, %2 offset:512\n\t"
                     "s_waitcnt lgkmcnt(0)"
                     : "=v"(v0), "=v"(v1) : "v"(vp) : "memory");
        __builtin_amdgcn_sched_barrier(0);
        union { bf16x4 hh[2]; bf16x8 full; } af;
        af.hh[0] = v0; af.hh[1] = v1;
        bf16x8 pf = *(const bf16x8*)(Pw + ((p15*128 + kh*64 + g*16) ^ ((p15 & 7) << 4)));
        acc_o[bb] = __builtin_amdgcn_mfma_f32_16x16x32_bf16(af.full, pf, acc_o[bb], 0, 0, 0);
      }
    }
  }

  const float inv = 1.0f / lsum;
  const size_t orow = (size_t)(b*Sz + q0 + p15)*Dz + hoff;
  #pragma unroll
  for (int bb = 0; bb < 4; ++bb) {
    ushort4 o;
    o.x = f2b(acc_o[bb][0]*inv);
    o.y = f2b(acc_o[bb][1]*inv);
    o.z = f2b(acc_o[bb][2]*inv);
    o.w = f2b(acc_o[bb][3]*inv);
    *(ushort4*)(ao + orow + 16*bb + 4*g) = o;
  }
}

// -------- LayerNorm 1: in = x + bo + op0 + op1 (fixed-order sum) --------
__global__ __launch_bounds__(256) void ln1_k(
    const float* __restrict__ x, const float* __restrict__ bo,
    const float* __restrict__ op, const float* __restrict__ g,
    const float* __restrict__ beta, float* __restrict__ outf,
    unsigned short* __restrict__ outb)
{
  int n = blockIdx.x, t = threadIdx.x;
  __shared__ float red[256];
  const float* op0 = op + (size_t)n*Dz;
  const float* op1 = op + (size_t)(Nz + n)*Dz;
  float vals[4]; float s = 0.f;
  #pragma unroll
  for (int i = 0; i < 4; ++i) {
    int d = t + i*256;
    float xv = x[(size_t)n*Dz + d] + bo[d] + (op0[d] + op1[d]);
    vals[i] = xv; s += xv;
  }
  red[t] = s; __syncthreads();
  for (int st = 128; st; st >>= 1) { if (t < st) red[t] += red[t+st]; __syncthreads(); }
  float mean = red[0] * (1.0f/Dz);
  __syncthreads();
  float vsum = 0.f;
  #pragma unroll
  for (int i = 0; i < 4; ++i){ float dd = vals[i]-mean; vsum += dd*dd; }
  red[t] = vsum; __syncthreads();
  for (int st = 128; st; st >>= 1) { if (t < st) red[t] += red[t+st]; __syncthreads(); }
  float rs = rsqrtf(red[0]*(1.0f/Dz) + EPSz);
  #pragma unroll
  for (int i = 0; i < 4; ++i) {
    int d = t + i*256;
    float o = (vals[i]-mean)*rs*g[d] + beta[d];
    outf[(size_t)n*Dz + d] = o;
    outb[(size_t)n*Dz + d] = f2b(o);
  }
}

// ---------------- gate ----------------
__global__ __launch_bounds__(64) void gate_topk(
    const float* __restrict__ x1, const float* __restrict__ Wg,
    const float* __restrict__ bg, int* __restrict__ counts,
    int* __restrict__ toklist, int4* __restrict__ tokinfo,
    float2* __restrict__ tokw)
{
  int n = blockIdx.x, lane = threadIdx.x;
  const float* row = x1 + (size_t)n*Dz;
  float acc[8] = {0,0,0,0,0,0,0,0};
  for (int d = lane; d < Dz; d += 64) {
    float xv = row[d];
    const float4* wp = (const float4*)(Wg + (size_t)d*Ez);
    float4 w0 = wp[0], w1 = wp[1];
    acc[0] += xv*w0.x; acc[1] += xv*w0.y; acc[2] += xv*w0.z; acc[3] += xv*w0.w;
    acc[4] += xv*w1.x; acc[5] += xv*w1.y; acc[6] += xv*w1.z; acc[7] += xv*w1.w;
  }
  #pragma unroll
  for (int e = 0; e < 8; ++e)
    #pragma unroll
    for (int off = 32; off; off >>= 1) acc[e] += __shfl_xor(acc[e], off);
  if (lane == 0) {
    float lg[8]; float mx = -INFINITY;
    #pragma unroll
    for (int e = 0; e < 8; ++e){ lg[e] = acc[e] + bg[e]; mx = fmaxf(mx, lg[e]); }
    float p[8];
    #pragma unroll
    for (int e = 0; e < 8; ++e) p[e] = __expf(lg[e]-mx);
    int e1 = 0; float m1 = p[0];
    for (int e = 1; e < 8; ++e) if (p[e] > m1){ m1 = p[e]; e1 = e; }
    int e2 = -1; float m2 = -INFINITY;
    for (int e = 0; e < 8; ++e) if (e != e1 && p[e] > m2){ m2 = p[e]; e2 = e; }
    float inv = 1.0f/(m1+m2);
    int p1 = atomicAdd(&counts[e1], 1); toklist[e1*Nz + p1] = n;
    int p2 = atomicAdd(&counts[e2], 1); toklist[e2*Nz + p2] = n;
    tokinfo[n] = make_int4(e1, p1, e2, p2);
    tokw[n] = make_float2(m1*inv, m2*inv);
  }
}

// ---------------- prefix + row-block table ----------------
__global__ void prefix_k(const int* __restrict__ counts, int* __restrict__ offs,
                         int2* __restrict__ rbmap){
  if (threadIdx.x == 0 && blockIdx.x == 0) {
    int s = 0;
    for (int e = 0; e < Ez; ++e){ offs[e] = s; s += counts[e]; }
    offs[Ez] = s;
    int rb = 0;
    for (int e = 0; e < Ez; ++e) {
      int nrb = (counts[e] + 127) >> 7;
      for (int i = 0; i < nrb; ++i) rbmap[rb++] = make_int2(e, i*128);
    }
    for (; rb < NRB; ++rb) rbmap[rb] = make_int2(-1, 0);
  }
}

// ------- final combine + LayerNorm (b2 + fixed-order partial sum) -------
__global__ __launch_bounds__(256) void ln2_k(
    const float* __restrict__ x1, const float* __restrict__ yp,
    const float* __restrict__ b2, const int4* __restrict__ tokinfo,
    const float2* __restrict__ tokw, const int* __restrict__ offs,
    const float* __restrict__ g, const float* __restrict__ beta,
    float* __restrict__ out)
{
  int n = blockIdx.x, t = threadIdx.x;
  __shared__ float red[256];
  int4 ti = tokinfo[n]; float2 tw = tokw[n];
  const int s1 = offs[ti.x] + ti.y;
  const int s2 = offs[ti.z] + ti.w;
  const float* yA0 = yp + (size_t)s1*Dz;
  const float* yA1 = yp + (size_t)(SLOTSz + s1)*Dz;
  const float* yB0 = yp + (size_t)s2*Dz;
  const float* yB1 = yp + (size_t)(SLOTSz + s2)*Dz;
  const float* b2a = b2 + (size_t)ti.x*Dz;
  const float* b2b = b2 + (size_t)ti.z*Dz;
  float vals[4]; float s = 0.f;
  #pragma unroll
  for (int i = 0; i < 4; ++i) {
    int d = t + i*256;
    float xv = x1[(size_t)n*Dz + d]
             + tw.x*((yA0[d] + yA1[d]) + b2a[d])
             + tw.y*((yB0[d] + yB1[d]) + b2b[d]);
    vals[i] = xv; s += xv;
  }
  red[t] = s; __syncthreads();
  for (int st = 128; st; st >>= 1) { if (t < st) red[t] += red[t+st]; __syncthreads(); }
  float mean = red[0] * (1.0f/Dz);
  __syncthreads();
  float vsum = 0.f;
  #pragma unroll
  for (int i = 0; i < 4; ++i){ float dd = vals[i]-mean; vsum += dd*dd; }
  red[t] = vsum; __syncthreads();
  for (int st = 128; st; st >>= 1) { if (t < st) red[t] += red[t+st]; __syncthreads(); }
  float rs = rsqrtf(red[0]*(1.0f/Dz) + EPSz);
  #pragma unroll
  for (int i = 0; i < 4; ++i) {
    int d = t + i*256;
    out[(size_t)n*Dz + d] = (vals[i]-mean)*rs*g[d] + beta[d];
  }
}

extern "C" void kernel_launch(void* const* d_in, const int* in_sizes, int n_in,
                              void* d_out, int out_size, void* d_ws, size_t ws_size,
                              hipStream_t stream)
{
  const float* x  = (const float*)d_in[0];
  const float* Wq = (const float*)d_in[1];
  const float* bq = (const float*)d_in[2];
  const float* Wk = (const float*)d_in[3];
  const float* bk = (const float*)d_in[4];
  const float* Wv = (const float*)d_in[5];
  const float* bv = (const float*)d_in[6];
  const float* Wo = (const float*)d_in[7];
  const float* bo = (const float*)d_in[8];
  const float* Wg = (const float*)d_in[9];
  const float* bg = (const float*)d_in[10];
  const float* W1 = (const float*)d_in[11];
  const float* b1 = (const float*)d_in[12];
  const float* W2 = (const float*)d_in[13];
  const float* b2 = (const float*)d_in[14];
  const float* g1 = (const float*)d_in[15];
  const float* be1= (const float*)d_in[16];
  const float* g2 = (const float*)d_in[17];
  const float* be2= (const float*)d_in[18];
  float* out = (float*)d_out;

  const size_t PD = (size_t)Dz*Dz;
  const size_t ND = (size_t)Nz*Dz;
  unsigned short* Wqt = (unsigned short*)d_ws;   // fused [3072][1024]
  unsigned short* Wkt = Wqt + PD;
  unsigned short* Wvt = Wkt + PD;
  unsigned short* Wot = Wvt + PD;
  unsigned short* W1t = Wot + PD;
  unsigned short* W2t = W1t + (size_t)Ez*FFz*Dz;
  unsigned short* hb  = W2t + (size_t)Ez*FFz*Dz;
  unsigned short* xb  = hb  + (size_t)SLOTSz*FFz;
  unsigned short* qkvb= xb  + ND;                 // [Nz][3072]
  unsigned short* aob = qkvb + (size_t)Nz*QKVSz;
  unsigned short* x1b = aob + ND;
  float* x1 = (float*)(x1b + ND);
  float* yp = x1 + ND;                            // [2][SLOTS][Dz] fp32 (32MB)
  float* op = yp;                                 // alias: [2][Nz][Dz], dead before yp written
  float* bqkv = yp + (size_t)2*SLOTSz*Dz;
  int4*  tokinfo = (int4*)(bqkv + QKVSz);
  float2* tokw   = (float2*)(tokinfo + Nz);
  int* counts  = (int*)(tokw + Nz);
  int* offs    = counts + Ez;
  int* toklist = offs + Ez + 1;
  int2* rbmap  = (int2*)(toklist + Ez*Nz);

  dim3 blk(256);
  transpose_cvt<<<dim3(16,16,1), blk, 0, stream>>>(Wq, Wqt, Dz, Dz);
  transpose_cvt<<<dim3(16,16,1), blk, 0, stream>>>(Wk, Wkt, Dz, Dz);
  transpose_cvt<<<dim3(16,16,1), blk, 0, stream>>>(Wv, Wvt, Dz, Dz);
  transpose_cvt<<<dim3(16,16,1), blk, 0, stream>>>(Wo, Wot, Dz, Dz);
  transpose_cvt<<<dim3(FFz/64, Dz/64, Ez), blk, 0, stream>>>(W1, W1t, Dz, FFz);
  transpose_cvt<<<dim3(Dz/64, FFz/64, Ez), blk, 0, stream>>>(W2, W2t, FFz, Dz);
  concat3<<<12, blk, 0, stream>>>(bq, bk, bv, bqkv);
  cvt_bf16<<<(int)(ND/4/256), blk, 0, stream>>>(x, xb, (int)ND);

  // fused QKV: [2048,1024] @ [1024,3072] -> qkvb (bf16 + bias)
  gemm_proj<<<dim3(QKVSz/128, Nz/128), blk, 0, stream>>>(
      xb, Wqt, bqkv, nullptr, qkvb, Nz, QKVSz, Dz, 1, 0);
  rope_qk<<<(Nz*Hz*32)/256, blk, 0, stream>>>(qkvb);
  attn_mfma<<<dim3(Bz*Hz*(Sz/64)), blk, 0, stream>>>(qkvb, qkvb + Dz, qkvb + 2*Dz, aob);

  // O projection: split-K x2 deterministic partials -> op[2][Nz][Dz]
  gemm_proj<<<dim3((Dz/128)*2, Nz/128), blk, 0, stream>>>(
      aob, Wot, nullptr, op, nullptr, Nz, Dz, Dz, 2, 1);
  ln1_k<<<Nz, blk, 0, stream>>>(x, bo, op, g1, be1, x1, x1b);

  hipMemsetAsync(counts, 0, Ez*sizeof(int), stream);
  gate_topk<<<Nz, dim3(64), 0, stream>>>(x1, Wg, bg, counts, toklist, tokinfo, tokw);
  prefix_k<<<1, dim3(64), 0, stream>>>(counts, offs, rbmap);
  moe_gemm1<<<dim3(FFz/128, NRB), blk, 0, stream>>>(x1b, W1t, b1, counts, offs, toklist, rbmap, hb);
  moe_gemm2<<<dim3((Dz/128)*2, NRB), blk, 0, stream>>>(hb, W2t, counts, offs, rbmap, yp);
  ln2_k<<<Nz, blk, 0, stream>>>(x1, yp, b2, tokinfo, tokw, offs, g2, be2, out);
}

// Round 8
// 431.431 us; speedup vs baseline: 7.8298x; 1.1450x over previous
//
#include <hip/hip_runtime.h>
#include <cmath>

#define Bz 2
#define Sz 1024
#define Dz 1024
#define Hz 16
#define HDz 64
#define Ez 8
#define FFz 4096
#define Nz (Bz*Sz)
#define SLOTSz (2*Nz)
#define QKVSz (3*Dz)
#define EPSz 1e-5f
#define NRB 40

typedef __attribute__((ext_vector_type(8))) short bf16x8;
typedef __attribute__((ext_vector_type(4))) short bf16x4;
typedef __attribute__((ext_vector_type(4))) float f32x4;
typedef __attribute__((ext_vector_type(8))) unsigned short ushortx8;

__device__ __forceinline__ float b2f(unsigned short u){
  union { unsigned int i; float f; } x; x.i = ((unsigned int)u) << 16; return x.f;
}
__device__ __forceinline__ unsigned short f2b(float f){
  union { float f; unsigned int i; } x; x.f = f;
  unsigned int r = x.i + 0x7FFFu + ((x.i >> 16) & 1u);
  return (unsigned short)(r >> 16);
}
__device__ __forceinline__ float erf_fast(float x){
  float ax = fabsf(x);
  float t = 1.0f/(1.0f + 0.3275911f*ax);
  float p = t*(0.254829592f + t*(-0.284496736f + t*(1.421413741f +
            t*(-1.453152027f + t*1.061405429f))));
  float r = 1.0f - p*__expf(-ax*ax);
  return copysignf(r, x);
}
__device__ __forceinline__ float gelu_f(float x){
  return 0.5f*x*(1.0f + erf_fast(x*0.70710678118654752f));
}
__device__ __forceinline__ void gload16(const void* g, void* l){
  __builtin_amdgcn_global_load_lds(
    (const __attribute__((address_space(1))) unsigned int*)g,
    (__attribute__((address_space(3))) unsigned int*)l, 16, 0, 0);
}

// ---------- shared transpose body: fp32 [R][C] tile -> bf16 [C][R] ----------
__device__ __forceinline__ void transpose_body(
    const float* __restrict__ in, unsigned short* __restrict__ out,
    int R, int C, int bx, int by, int tid, float (*tile)[65])
{
  int c0 = bx*64, r0 = by*64;
  int tx = tid & 15, ty = tid >> 4;
  #pragma unroll
  for (int i = 0; i < 4; ++i) {
    float4 v = *(const float4*)(in + (size_t)(r0+ty+16*i)*C + c0 + tx*4);
    tile[ty+16*i][tx*4+0] = v.x; tile[ty+16*i][tx*4+1] = v.y;
    tile[ty+16*i][tx*4+2] = v.z; tile[ty+16*i][tx*4+3] = v.w;
  }
  __syncthreads();
  int oc = tid >> 3, og = tid & 7;
  #pragma unroll
  for (int p = 0; p < 2; ++p) {
    int c = oc + p*32;
    ushortx8 u;
    #pragma unroll
    for (int j = 0; j < 8; ++j) u[j] = f2b(tile[og*8+j][c]);
    *(ushortx8*)(out + (size_t)(c0+c)*R + r0 + og*8) = u;
  }
}

// ---------- fused prologue: Wq/Wk/Wv/Wo transpose + bias concat + x->bf16 ----------
__global__ __launch_bounds__(256) void prologue_k(
    const float* __restrict__ Wq, const float* __restrict__ Wk,
    const float* __restrict__ Wv, const float* __restrict__ Wo,
    const float* __restrict__ bq, const float* __restrict__ bk,
    const float* __restrict__ bv, const float* __restrict__ x,
    unsigned short* __restrict__ Wqt, unsigned short* __restrict__ Wkt,
    unsigned short* __restrict__ Wvt, unsigned short* __restrict__ Wot,
    float* __restrict__ bqkv, unsigned short* __restrict__ xb)
{
  __shared__ float tile[64][65];
  int id = blockIdx.x, t = threadIdx.x;
  if (id < 1024) {
    int which = id >> 8, rem = id & 255;
    const float* in = (which==0)?Wq:(which==1)?Wk:(which==2)?Wv:Wo;
    unsigned short* out = (which==0)?Wqt:(which==1)?Wkt:(which==2)?Wvt:Wot;
    transpose_body(in, out, Dz, Dz, rem & 15, rem >> 4, t, tile);
  } else if (id < 1024 + 2048) {
    int i = ((id-1024)*256 + t)*4;
    float4 v = *(const float4*)(x + i);
    ushort4 o; o.x=f2b(v.x); o.y=f2b(v.y); o.z=f2b(v.z); o.w=f2b(v.w);
    *(ushort4*)(xb + i) = o;
  } else {
    int i = (id - 3072)*256 + t;
    if (i < 3072) bqkv[i] = (i < 1024) ? bq[i] : (i < 2048 ? bk[i-1024] : bv[i-2048]);
  }
}

// ------- MFMA 128x128xK core: 3-buffer pipeline, counted vmcnt --------
__device__ __forceinline__ void mfma_kloop(
    const unsigned short* __restrict__ pA0,
    const unsigned short* __restrict__ pB0,
    char* lds, int t, int K, f32x4 acc[4][4])
{
  const int lane = t & 63, w = t >> 6;
  const int wr = (w >> 1) << 6, wc = (w & 1) << 6;
  const int iA = (lane >> 4)*128 + wr + (lane & 15);
  const int iB = (lane >> 4)*128 + wc + (lane & 15);
#define STAGEK(bi, k0) do { \
    char* _b = lds + (bi)*16384; \
    gload16(pA0 + (k0),      _b + t*16); \
    gload16(pA0 + (k0) + 16, _b + (256+t)*16); \
    gload16(pB0 + (k0),      _b + 8192 + t*16); \
    gload16(pB0 + (k0) + 16, _b + 8192 + (256+t)*16); \
  } while(0)
#define WAITBAR4 do { __builtin_amdgcn_sched_barrier(0); \
    asm volatile("s_waitcnt vmcnt(4) lgkmcnt(0)\n\ts_barrier" ::: "memory"); \
    __builtin_amdgcn_sched_barrier(0); } while(0)
#define WAITBAR0 do { __builtin_amdgcn_sched_barrier(0); \
    asm volatile("s_waitcnt vmcnt(0) lgkmcnt(0)\n\ts_barrier" ::: "memory"); \
    __builtin_amdgcn_sched_barrier(0); } while(0)
  const int nt = K >> 5;
  STAGEK(0, 0);
  if (nt > 1) { STAGEK(1, 32); WAITBAR4; }
  else        {                WAITBAR0; }
  int cur = 0;
  for (int ti = 0; ti < nt; ++ti) {
    const bool more = (ti + 2 < nt);
    if (more) {
      int stg = cur + 2; if (stg >= 3) stg -= 3;
      STAGEK(stg, (ti + 2) << 5);
    }
    const bf16x8* fA = (const bf16x8*)(lds + cur*16384);
    const bf16x8* fB = (const bf16x8*)(lds + cur*16384 + 8192);
    bf16x8 a[4], b[4];
    #pragma unroll
    for (int m = 0; m < 4; ++m) a[m] = fA[iA + m*16];
    #pragma unroll
    for (int n = 0; n < 4; ++n) b[n] = fB[iB + n*16];
    #pragma unroll
    for (int m = 0; m < 4; ++m)
      #pragma unroll
      for (int n = 0; n < 4; ++n)
        acc[m][n] = __builtin_amdgcn_mfma_f32_16x16x32_bf16(a[m], b[n], acc[m][n], 0, 0, 0);
    if (more) WAITBAR4; else WAITBAR0;
    cur += 1; if (cur >= 3) cur -= 3;
  }
#undef STAGEK
#undef WAITBAR4
#undef WAITBAR0
}

// ---------------- dense GEMM with optional split-K (deterministic) ----------------
// mode 0: outb = f2b(acc + bias[col]); mode 1: outb[(chunk*M+row)*Nn+col] = f2b(acc)
__global__ __launch_bounds__(256) void gemm_proj(
    const unsigned short* __restrict__ A, const unsigned short* __restrict__ Bt,
    const float* __restrict__ bias, unsigned short* __restrict__ outb,
    int M, int Nn, int K, int KS, int mode)
{
  __shared__ __align__(16) char lds[49152];
  const int t = threadIdx.x;
  const int nblk = Nn >> 7;
  const int chunk = blockIdx.x / nblk;
  const int n0 = (blockIdx.x - chunk*nblk) << 7;
  const int m0 = blockIdx.y << 7;
  const int Kc = K / KS;
  const int kbase = chunk * Kc;
  const int ridx = t & 127, kc = t >> 7;
  const unsigned short* pA0 = A + (size_t)(m0 + ridx)*K + kbase + kc*8;
  const unsigned short* pB0 = Bt + (size_t)(n0 + ridx)*K + kbase + kc*8;
  f32x4 acc[4][4] = {};
  mfma_kloop(pA0, pB0, lds, t, Kc, acc);
  const int lane = t & 63, w = t >> 6;
  const int wr = (w>>1)<<6, wc = (w&1)<<6, lq = lane>>4, lr = lane&15;
  #pragma unroll
  for (int m = 0; m < 4; ++m)
    #pragma unroll
    for (int r = 0; r < 4; ++r) {
      int row = m0 + wr + m*16 + lq*4 + r;
      #pragma unroll
      for (int n = 0; n < 4; ++n) {
        int col = n0 + wc + n*16 + lr;
        if (mode == 0) outb[(size_t)row*Nn + col] = f2b(acc[m][n][r] + bias[col]);
        else outb[((size_t)chunk*M + row)*Nn + col] = f2b(acc[m][n][r]);
      }
    }
}

// ---------------- grouped MoE GEMM1 (row-block table) ----------------
__global__ __launch_bounds__(256) void moe_gemm1(
    const unsigned short* __restrict__ x1b, const unsigned short* __restrict__ W1t,
    const float* __restrict__ b1, const int* __restrict__ counts,
    const int* __restrict__ offs, const int* __restrict__ toklist,
    const int2* __restrict__ rbmap, unsigned short* __restrict__ hb)
{
  const int2 rbe = rbmap[blockIdx.y];
  if (rbe.x < 0) return;
  const int e = rbe.x, r0 = rbe.y, cnt = counts[e];
  __shared__ __align__(16) char lds[49152];
  const int t = threadIdx.x, n0 = blockIdx.x*128;
  const int ridx = t & 127, kc = t >> 7;
  const int rg = r0 + ridx;
  const int tok = toklist[e*Nz + (rg < cnt ? rg : 0)];
  const unsigned short* pA0 = x1b + (size_t)tok*Dz + kc*8;
  const unsigned short* pB0 = W1t + ((size_t)e*FFz + n0 + ridx)*Dz + kc*8;
  f32x4 acc[4][4] = {};
  mfma_kloop(pA0, pB0, lds, t, Dz, acc);
  const int lane = t & 63, w = t >> 6;
  const int wr = (w>>1)<<6, wc = (w&1)<<6, lq = lane>>4, lr = lane&15;
  const int base = offs[e] + r0;
  #pragma unroll
  for (int m = 0; m < 4; ++m)
    #pragma unroll
    for (int r = 0; r < 4; ++r) {
      int row = wr + m*16 + lq*4 + r;
      if (r0 + row >= cnt) continue;
      #pragma unroll
      for (int n = 0; n < 4; ++n) {
        int col = n0 + wc + n*16 + lr;
        hb[(size_t)(base+row)*FFz + col] = f2b(gelu_f(acc[m][n][r] + b1[e*FFz + col]));
      }
    }
}

// ------- grouped MoE GEMM2, split-K x4 -> per-chunk bf16 partial stores -------
__global__ __launch_bounds__(256) void moe_gemm2(
    const unsigned short* __restrict__ hb, const unsigned short* __restrict__ W2t,
    const int* __restrict__ counts, const int* __restrict__ offs,
    const int2* __restrict__ rbmap, unsigned short* __restrict__ yp)
{
  const int2 rbe = rbmap[blockIdx.y];
  if (rbe.x < 0) return;
  const int e = rbe.x, r0 = rbe.y, cnt = counts[e];
  __shared__ __align__(16) char lds[49152];
  const int t = threadIdx.x;
  const int chunk = blockIdx.x >> 3;
  const int n0 = (blockIdx.x & 7) << 7;
  const int kbase = chunk * (FFz/4);
  const int ridx = t & 127, kc = t >> 7;
  const int rg = r0 + ridx;
  const int slot = offs[e] + (rg < cnt ? rg : 0);
  const unsigned short* pA0 = hb + (size_t)slot*FFz + kbase + kc*8;
  const unsigned short* pB0 = W2t + ((size_t)e*Dz + n0 + ridx)*FFz + kbase + kc*8;
  f32x4 acc[4][4] = {};
  mfma_kloop(pA0, pB0, lds, t, FFz/4, acc);
  const int lane = t & 63, w = t >> 6;
  const int wr = (w>>1)<<6, wc = (w&1)<<6, lq = lane>>4, lr = lane&15;
  const int base = offs[e] + r0;
  #pragma unroll
  for (int m = 0; m < 4; ++m)
    #pragma unroll
    for (int r = 0; r < 4; ++r) {
      int row = wr + m*16 + lq*4 + r;
      if (r0 + row >= cnt) continue;
      #pragma unroll
      for (int n = 0; n < 4; ++n) {
        int col = n0 + wc + n*16 + lr;
        yp[((size_t)chunk*SLOTSz + base + row)*Dz + col] = f2b(acc[m][n][r]);
      }
    }
}

// ---------------- RoPE (in-place on fused qkv buffer) ----------------
__global__ void rope_qk(unsigned short* __restrict__ qkv){
  int gid = blockIdx.x*blockDim.x + threadIdx.x;
  int i = gid & 31;
  int h = (gid >> 5) & (Hz-1);
  int n = gid >> 9;
  int s = n & (Sz-1);
  float inv = powf(10000.0f, -(float)(2*i)/64.0f);
  float ang = (float)s * inv;
  float cs = cosf(ang), sn = sinf(ang);
  size_t base = (size_t)n*QKVSz + h*HDz + i;
  float q1 = b2f(qkv[base]), q2 = b2f(qkv[base+32]);
  qkv[base]    = f2b(q1*cs - q2*sn);
  qkv[base+32] = f2b(q2*cs + q1*sn);
  float k1 = b2f(qkv[base+Dz]), k2 = b2f(qkv[base+Dz+32]);
  qkv[base+Dz]    = f2b(k1*cs - k2*sn);
  qkv[base+Dz+32] = f2b(k2*cs + k1*sn);
}

// ----- MEGA: attention (blocks 0..511) + W1/W2 transpose-convert (rest) -----
__global__ __launch_bounds__(256) void mega_k(
    const unsigned short* __restrict__ qkv, unsigned short* __restrict__ ao,
    const float* __restrict__ W1, unsigned short* __restrict__ W1t,
    const float* __restrict__ W2, unsigned short* __restrict__ W2t)
{
  __shared__ __align__(16) char smem[24576];
  const int bid = blockIdx.x;
  if (bid >= 512) {
    if (bid < 512 + 8192) {
      int rem = bid - 512; int e = rem >> 10; int r = rem & 1023;
      transpose_body(W1 + (size_t)e*Dz*FFz, W1t + (size_t)e*FFz*Dz, Dz, FFz,
                     r & 63, r >> 6, threadIdx.x, (float(*)[65])smem);
    } else {
      int rem = bid - 8704; int e = rem >> 10; int r = rem & 1023;
      transpose_body(W2 + (size_t)e*FFz*Dz, W2t + (size_t)e*Dz*FFz, FFz, Dz,
                     r & 15, r >> 4, threadIdx.x, (float(*)[65])smem);
    }
    return;
  }
  // ---- attention ----
  char* Klds = smem;
  char* Vlds = smem + 8192;
  char* Plds = smem + 16384;
  const unsigned short* q = qkv;
  const unsigned short* k = qkv + Dz;
  const unsigned short* v = qkv + 2*Dz;

  const int t = threadIdx.x;
  const int lane = t & 63, w = t >> 6;
  const int p15 = lane & 15, g = lane >> 4;
  const int bh = bid >> 4;
  const int qblk = bid & 15;
  const int b = bh >> 4, h = bh & 15;
  const size_t hoff = (size_t)h*HDz;
  const int q0 = qblk*64 + w*16;

  const size_t qrow = (size_t)(b*Sz + q0 + p15)*QKVSz + hoff;
  const bf16x8 qf0 = *(const bf16x8*)(q + qrow + 8*g);
  const bf16x8 qf1 = *(const bf16x8*)(q + qrow + 32 + 8*g);

  char* Pw = Plds + w*2048;

  float mrun = -INFINITY, lsum = 0.f;
  f32x4 acc_o[4] = {};

  const unsigned short* kbh = k + (size_t)(b*Sz)*QKVSz + hoff;
  const unsigned short* vbh = v + (size_t)(b*Sz)*QKVSz + hoff;

  for (int t0 = 0; t0 < Sz; t0 += 64) {
    __syncthreads();
    #pragma unroll
    for (int u = 0; u < 2; ++u) {
      int j = t + 256*u;
      int kkv = j >> 3, kdc = (j & 7) ^ (kkv & 7);
      gload16(kbh + (size_t)(t0 + kkv)*QKVSz + 8*kdc, Klds + j*16);
      int va = j >> 5, vbb = (j >> 3) & 3, vr = (j >> 1) & 3, vc = 8*(j & 1);
      gload16(vbh + (size_t)(t0 + 4*va + vr)*QKVSz + 16*vbb + vc, Vlds + j*16);
    }
    __syncthreads();

    f32x4 sc[4];
    #pragma unroll
    for (int mt = 0; mt < 4; ++mt) {
      int kv = mt*16 + p15;
      bf16x8 a0 = *(const bf16x8*)(Klds + kv*128 + ((g     ^ (kv & 7))*16));
      bf16x8 a1 = *(const bf16x8*)(Klds + kv*128 + (((g+4) ^ (kv & 7))*16));
      f32x4 z = {};
      z = __builtin_amdgcn_mfma_f32_16x16x32_bf16(a0, qf0, z, 0, 0, 0);
      z = __builtin_amdgcn_mfma_f32_16x16x32_bf16(a1, qf1, z, 0, 0, 0);
      sc[mt] = z;
    }

    float pmax = -INFINITY;
    #pragma unroll
    for (int mt = 0; mt < 4; ++mt)
      #pragma unroll
      for (int r = 0; r < 4; ++r) {
        sc[mt][r] *= 0.125f;
        pmax = fmaxf(pmax, sc[mt][r]);
      }
    pmax = fmaxf(pmax, __shfl_xor(pmax, 16));
    pmax = fmaxf(pmax, __shfl_xor(pmax, 32));
    float mnew = fmaxf(mrun, pmax);
    float resc = __expf(mrun - mnew);
    mrun = mnew;
    float ps = 0.f;
    #pragma unroll
    for (int mt = 0; mt < 4; ++mt) {
      float p0 = __expf(sc[mt][0] - mnew);
      float p1 = __expf(sc[mt][1] - mnew);
      float p2 = __expf(sc[mt][2] - mnew);
      float p3 = __expf(sc[mt][3] - mnew);
      ps += (p0 + p1) + (p2 + p3);
      ushort4 pk;
      pk.x = f2b(p0); pk.y = f2b(p1); pk.z = f2b(p2); pk.w = f2b(p3);
      *(ushort4*)(Pw + ((p15*128 + mt*32 + g*8) ^ ((p15 & 7) << 4))) = pk;
    }
    ps += __shfl_xor(ps, 16);
    ps += __shfl_xor(ps, 32);
    lsum = lsum*resc + ps;
    #pragma unroll
    for (int bb = 0; bb < 4; ++bb) {
      acc_o[bb][0] *= resc; acc_o[bb][1] *= resc;
      acc_o[bb][2] *= resc; acc_o[bb][3] *= resc;
    }

    #pragma unroll
    for (int bb = 0; bb < 4; ++bb) {
      #pragma unroll
      for (int kh = 0; kh < 2; ++kh) {
        const __attribute__((address_space(3))) char* vp =
          (const __attribute__((address_space(3))) char*)
            (Vlds + 4096*kh + 1024*g + 128*bb + 8*p15);
        bf16x4 v0, v1;
        asm volatile("ds_read_b64_tr_b16 %0, %2\n\t"
                     "ds_read_b64_tr_b16 %1, %2 offset:512\n\t"
                     "s_waitcnt lgkmcnt(0)"
                     : "=v"(v0), "=v"(v1) : "v"(vp) : "memory");
        __builtin_amdgcn_sched_barrier(0);
        union { bf16x4 hh[2]; bf16x8 full; } af;
        af.hh[0] = v0; af.hh[1] = v1;
        bf16x8 pf = *(const bf16x8*)(Pw + ((p15*128 + kh*64 + g*16) ^ ((p15 & 7) << 4)));
        acc_o[bb] = __builtin_amdgcn_mfma_f32_16x16x32_bf16(af.full, pf, acc_o[bb], 0, 0, 0);
      }
    }
  }

  const float inv = 1.0f / lsum;
  const size_t orow = (size_t)(b*Sz + q0 + p15)*Dz + hoff;
  #pragma unroll
  for (int bb = 0; bb < 4; ++bb) {
    ushort4 o;
    o.x = f2b(acc_o[bb][0]*inv);
    o.y = f2b(acc_o[bb][1]*inv);
    o.z = f2b(acc_o[bb][2]*inv);
    o.w = f2b(acc_o[bb][3]*inv);
    *(ushort4*)(ao + orow + 16*bb + 4*g) = o;
  }
}

// -------- LayerNorm 1: in = x + bo + sum4(bf16 partials), fixed order --------
__global__ __launch_bounds__(256) void ln1_k(
    const float* __restrict__ x, const float* __restrict__ bo,
    const unsigned short* __restrict__ op, const float* __restrict__ g,
    const float* __restrict__ beta, float* __restrict__ outf,
    unsigned short* __restrict__ outb)
{
  int n = blockIdx.x, t = threadIdx.x;
  __shared__ float red[256];
  float vals[4]; float s = 0.f;
  #pragma unroll
  for (int i = 0; i < 4; ++i) {
    int d = t + i*256;
    size_t idx = (size_t)n*Dz + d;
    float p0 = b2f(op[idx]);
    float p1 = b2f(op[(size_t)Nz*Dz + idx]);
    float p2 = b2f(op[(size_t)2*Nz*Dz + idx]);
    float p3 = b2f(op[(size_t)3*Nz*Dz + idx]);
    float xv = x[idx] + bo[d] + ((p0 + p1) + (p2 + p3));
    vals[i] = xv; s += xv;
  }
  red[t] = s; __syncthreads();
  for (int st = 128; st; st >>= 1) { if (t < st) red[t] += red[t+st]; __syncthreads(); }
  float mean = red[0] * (1.0f/Dz);
  __syncthreads();
  float vsum = 0.f;
  #pragma unroll
  for (int i = 0; i < 4; ++i){ float dd = vals[i]-mean; vsum += dd*dd; }
  red[t] = vsum; __syncthreads();
  for (int st = 128; st; st >>= 1) { if (t < st) red[t] += red[t+st]; __syncthreads(); }
  float rs = rsqrtf(red[0]*(1.0f/Dz) + EPSz);
  #pragma unroll
  for (int i = 0; i < 4; ++i) {
    int d = t + i*256;
    float o = (vals[i]-mean)*rs*g[d] + beta[d];
    outf[(size_t)n*Dz + d] = o;
    outb[(size_t)n*Dz + d] = f2b(o);
  }
}

// ---------------- gate ----------------
__global__ __launch_bounds__(64) void gate_topk(
    const float* __restrict__ x1, const float* __restrict__ Wg,
    const float* __restrict__ bg, int* __restrict__ counts,
    int* __restrict__ toklist, int4* __restrict__ tokinfo,
    float2* __restrict__ tokw)
{
  int n = blockIdx.x, lane = threadIdx.x;
  const float* row = x1 + (size_t)n*Dz;
  float acc[8] = {0,0,0,0,0,0,0,0};
  for (int d = lane; d < Dz; d += 64) {
    float xv = row[d];
    const float4* wp = (const float4*)(Wg + (size_t)d*Ez);
    float4 w0 = wp[0], w1 = wp[1];
    acc[0] += xv*w0.x; acc[1] += xv*w0.y; acc[2] += xv*w0.z; acc[3] += xv*w0.w;
    acc[4] += xv*w1.x; acc[5] += xv*w1.y; acc[6] += xv*w1.z; acc[7] += xv*w1.w;
  }
  #pragma unroll
  for (int e = 0; e < 8; ++e)
    #pragma unroll
    for (int off = 32; off; off >>= 1) acc[e] += __shfl_xor(acc[e], off);
  if (lane == 0) {
    float lg[8]; float mx = -INFINITY;
    #pragma unroll
    for (int e = 0; e < 8; ++e){ lg[e] = acc[e] + bg[e]; mx = fmaxf(mx, lg[e]); }
    float p[8];
    #pragma unroll
    for (int e = 0; e < 8; ++e) p[e] = __expf(lg[e]-mx);
    int e1 = 0; float m1 = p[0];
    for (int e = 1; e < 8; ++e) if (p[e] > m1){ m1 = p[e]; e1 = e; }
    int e2 = -1; float m2 = -INFINITY;
    for (int e = 0; e < 8; ++e) if (e != e1 && p[e] > m2){ m2 = p[e]; e2 = e; }
    float inv = 1.0f/(m1+m2);
    int p1 = atomicAdd(&counts[e1], 1); toklist[e1*Nz + p1] = n;
    int p2 = atomicAdd(&counts[e2], 1); toklist[e2*Nz + p2] = n;
    tokinfo[n] = make_int4(e1, p1, e2, p2);
    tokw[n] = make_float2(m1*inv, m2*inv);
  }
}

// ---------------- prefix + row-block table ----------------
__global__ void prefix_k(const int* __restrict__ counts, int* __restrict__ offs,
                         int2* __restrict__ rbmap){
  if (threadIdx.x == 0 && blockIdx.x == 0) {
    int s = 0;
    for (int e = 0; e < Ez; ++e){ offs[e] = s; s += counts[e]; }
    offs[Ez] = s;
    int rb = 0;
    for (int e = 0; e < Ez; ++e) {
      int nrb = (counts[e] + 127) >> 7;
      for (int i = 0; i < nrb; ++i) rbmap[rb++] = make_int2(e, i*128);
    }
    for (; rb < NRB; ++rb) rbmap[rb] = make_int2(-1, 0);
  }
}

// ------- final combine + LayerNorm (b2 + fixed-order bf16 partial sum) -------
__global__ __launch_bounds__(256) void ln2_k(
    const float* __restrict__ x1, const unsigned short* __restrict__ yp,
    const float* __restrict__ b2, const int4* __restrict__ tokinfo,
    const float2* __restrict__ tokw, const int* __restrict__ offs,
    const float* __restrict__ g, const float* __restrict__ beta,
    float* __restrict__ out)
{
  int n = blockIdx.x, t = threadIdx.x;
  __shared__ float red[256];
  int4 ti = tokinfo[n]; float2 tw = tokw[n];
  const size_t s1 = (size_t)(offs[ti.x] + ti.y)*Dz;
  const size_t s2 = (size_t)(offs[ti.z] + ti.w)*Dz;
  const size_t CS = (size_t)SLOTSz*Dz;
  const float* b2a = b2 + (size_t)ti.x*Dz;
  const float* b2b = b2 + (size_t)ti.z*Dz;
  float vals[4]; float s = 0.f;
  #pragma unroll
  for (int i = 0; i < 4; ++i) {
    int d = t + i*256;
    float a0 = b2f(yp[s1 + d]);
    float a1 = b2f(yp[CS + s1 + d]);
    float a2 = b2f(yp[2*CS + s1 + d]);
    float a3 = b2f(yp[3*CS + s1 + d]);
    float c0 = b2f(yp[s2 + d]);
    float c1 = b2f(yp[CS + s2 + d]);
    float c2 = b2f(yp[2*CS + s2 + d]);
    float c3 = b2f(yp[3*CS + s2 + d]);
    float sumA = (a0 + a1) + (a2 + a3);
    float sumB = (c0 + c1) + (c2 + c3);
    float xv = x1[(size_t)n*Dz + d] + tw.x*(sumA + b2a[d]) + tw.y*(sumB + b2b[d]);
    vals[i] = xv; s += xv;
  }
  red[t] = s; __syncthreads();
  for (int st = 128; st; st >>= 1) { if (t < st) red[t] += red[t+st]; __syncthreads(); }
  float mean = red[0] * (1.0f/Dz);
  __syncthreads();
  float vsum = 0.f;
  #pragma unroll
  for (int i = 0; i < 4; ++i){ float dd = vals[i]-mean; vsum += dd*dd; }
  red[t] = vsum; __syncthreads();
  for (int st = 128; st; st >>= 1) { if (t < st) red[t] += red[t+st]; __syncthreads(); }
  float rs = rsqrtf(red[0]*(1.0f/Dz) + EPSz);
  #pragma unroll
  for (int i = 0; i < 4; ++i) {
    int d = t + i*256;
    out[(size_t)n*Dz + d] = (vals[i]-mean)*rs*g[d] + beta[d];
  }
}

extern "C" void kernel_launch(void* const* d_in, const int* in_sizes, int n_in,
                              void* d_out, int out_size, void* d_ws, size_t ws_size,
                              hipStream_t stream)
{
  const float* x  = (const float*)d_in[0];
  const float* Wq = (const float*)d_in[1];
  const float* bq = (const float*)d_in[2];
  const float* Wk = (const float*)d_in[3];
  const float* bk = (const float*)d_in[4];
  const float* Wv = (const float*)d_in[5];
  const float* bv = (const float*)d_in[6];
  const float* Wo = (const float*)d_in[7];
  const float* bo = (const float*)d_in[8];
  const float* Wg = (const float*)d_in[9];
  const float* bg = (const float*)d_in[10];
  const float* W1 = (const float*)d_in[11];
  const float* b1 = (const float*)d_in[12];
  const float* W2 = (const float*)d_in[13];
  const float* b2 = (const float*)d_in[14];
  const float* g1 = (const float*)d_in[15];
  const float* be1= (const float*)d_in[16];
  const float* g2 = (const float*)d_in[17];
  const float* be2= (const float*)d_in[18];
  float* out = (float*)d_out;

  const size_t PD = (size_t)Dz*Dz;
  const size_t ND = (size_t)Nz*Dz;
  unsigned short* Wqt = (unsigned short*)d_ws;
  unsigned short* Wkt = Wqt + PD;
  unsigned short* Wvt = Wkt + PD;
  unsigned short* Wot = Wvt + PD;
  unsigned short* W1t = Wot + PD;
  unsigned short* W2t = W1t + (size_t)Ez*FFz*Dz;
  unsigned short* hb  = W2t + (size_t)Ez*FFz*Dz;
  unsigned short* xb  = hb  + (size_t)SLOTSz*FFz;
  unsigned short* qkvb= xb  + ND;                 // [Nz][3072]
  unsigned short* aob = qkvb + (size_t)Nz*QKVSz;
  unsigned short* x1b = aob + ND;
  float* x1 = (float*)(x1b + ND);
  unsigned short* yp = (unsigned short*)(x1 + ND); // [4][SLOTS][Dz] bf16 (32MB)
  unsigned short* op = yp;                         // alias: [4][Nz][Dz] bf16
  float* bqkv = (float*)(yp + (size_t)4*SLOTSz*Dz);
  int4*  tokinfo = (int4*)(bqkv + QKVSz);
  float2* tokw   = (float2*)(tokinfo + Nz);
  int* counts  = (int*)(tokw + Nz);
  int* offs    = counts + Ez;
  int* toklist = offs + Ez + 1;
  int2* rbmap  = (int2*)(toklist + Ez*Nz);

  dim3 blk(256);
  // fused prologue: Wq/Wk/Wv/Wo transpose + bias concat + x->bf16
  prologue_k<<<3084, blk, 0, stream>>>(Wq, Wk, Wv, Wo, bq, bk, bv, x,
                                       Wqt, Wkt, Wvt, Wot, bqkv, xb);

  // fused QKV: [2048,1024] @ [1024,3072] -> qkvb (bf16 + bias)
  gemm_proj<<<dim3(QKVSz/128, Nz/128), blk, 0, stream>>>(
      xb, Wqt, bqkv, qkvb, Nz, QKVSz, Dz, 1, 0);
  rope_qk<<<(Nz*Hz*32)/256, blk, 0, stream>>>(qkvb);

  // MEGA: attention + W1/W2 transpose-convert
  mega_k<<<512 + 2*8192, blk, 0, stream>>>(qkvb, aob, W1, W1t, W2, W2t);

  // O projection: split-K x4 deterministic bf16 partials -> op[4][Nz][Dz]
  gemm_proj<<<dim3((Dz/128)*4, Nz/128), blk, 0, stream>>>(
      aob, Wot, nullptr, op, Nz, Dz, Dz, 4, 1);
  ln1_k<<<Nz, blk, 0, stream>>>(x, bo, op, g1, be1, x1, x1b);

  hipMemsetAsync(counts, 0, Ez*sizeof(int), stream);
  gate_topk<<<Nz, dim3(64), 0, stream>>>(x1, Wg, bg, counts, toklist, tokinfo, tokw);
  prefix_k<<<1, dim3(64), 0, stream>>>(counts, offs, rbmap);
  moe_gemm1<<<dim3(FFz/128, NRB), blk, 0, stream>>>(x1b, W1t, b1, counts, offs, toklist, rbmap, hb);
  moe_gemm2<<<dim3((Dz/128)*4, NRB), blk, 0, stream>>>(hb, W2t, counts, offs, rbmap, yp);
  ln2_k<<<Nz, blk, 0, stream>>>(x1, yp, b2, tokinfo, tokw, offs, g2, be2, out);
}